// Round 1
// 323.380 us; speedup vs baseline: 1.0489x; 1.0489x over previous
//
#include <hip/hip_runtime.h>

typedef unsigned long long u64;
typedef unsigned short ushort_t;
typedef unsigned int uint32;

#define NNODES 12288
#define WORDS 192    // 12288 / 64 bits per row
#define ELLW 256     // max neighbors per row (avg ~64)
#define ZROW NNODES  // zeroed pad row index
#define LDB 520      // LDS A-frag block stride in shorts (bank-rotates by 4 words/block)

typedef __attribute__((ext_vector_type(8))) short short8_t;   // 8 bf16 (4 VGPRs)
typedef __attribute__((ext_vector_type(4))) float f32x4;      // MFMA C/D frag

// ---- bf16 split helpers (RNE) ----
__device__ __forceinline__ ushort_t f2bf(float f) {
    uint32 u = __float_as_uint(f);
    return (ushort_t)((u + 0x7fffu + ((u >> 16) & 1u)) >> 16);
}
__device__ __forceinline__ float bf2f(ushort_t h) {
    return __uint_as_float(((uint32)h) << 16);
}

// ---------------- adjacency build: bitmask M[s][d], MT[d][s] ----------------
__global__ void build_mask_kernel(const int* __restrict__ ei, u64* __restrict__ M,
                                  u64* __restrict__ MT, int E) {
    int e = blockIdx.x * blockDim.x + threadIdx.x;
    if (e >= E) return;
    int s = ei[e];
    int d = ei[E + e];
    atomicOr(&M[(size_t)s * WORDS + (d >> 6)], 1ull << (d & 63));
    atomicOr(&MT[(size_t)d * WORDS + (s >> 6)], 1ull << (s & 63));
}

// ---------------- bitmask -> u16 ELL (padded to x8 with ZROW) ----------------
__global__ __launch_bounds__(256) void ell_fill_kernel(
        const u64* __restrict__ M, const u64* __restrict__ MT,
        ushort_t* __restrict__ ell, int* __restrict__ cnt, float* __restrict__ dinv) {
    int row = blockIdx.x * 4 + (threadIdx.x >> 6);
    int lane = threadIdx.x & 63;
    const u64* rM  = M  + (size_t)row * WORDS;
    const u64* rMT = MT + (size_t)row * WORDS;
    u64 wm[3], wt[3];
    int pm = 0, pt = 0;
    #pragma unroll
    for (int k = 0; k < 3; ++k) {
        wm[k] = rM[lane + 64 * k];  pm += __popcll(wm[k]);
        wt[k] = rMT[lane + 64 * k]; pt += __popcll(wt[k]);
    }
    int inclM = pm, inclT = pt;
    #pragma unroll
    for (int off = 1; off < 64; off <<= 1) {
        int ym = __shfl_up(inclM, off, 64);
        int yt = __shfl_up(inclT, off, 64);
        if (lane >= off) { inclM += ym; inclT += yt; }
    }
    int exclM = inclM - pm;
    int exclT = inclT - pt;
    int totM = __shfl(inclM, 63, 64);
    int totT = __shfl(inclT, 63, 64);
    ushort_t* out = ell + (size_t)row * ELLW;
    int pos = exclM;
    #pragma unroll
    for (int k = 0; k < 3; ++k) {
        u64 bits = wm[k];
        int base = (lane + 64 * k) << 6;
        while (bits) { out[pos++] = (ushort_t)(base + __builtin_ctzll(bits)); bits &= bits - 1; }
    }
    pos = totM + exclT;
    #pragma unroll
    for (int k = 0; k < 3; ++k) {
        u64 bits = wt[k];
        int base = (lane + 64 * k) << 6;
        while (bits) { out[pos++] = (ushort_t)(base + __builtin_ctzll(bits)); bits &= bits - 1; }
    }
    if (lane == 0) {
        int n = totM + totT;
        int np = (n + 7) & ~7;
        for (int p = n; p < np; ++p) out[p] = (ushort_t)ZROW;
        cnt[row] = n;
        dinv[row] = 1.0f / ((float)n + 1e-8f);
    }
}

// ---------------- weight prep: split + B-FRAGMENT SWIZZLE + X pad clear ------
__global__ void wprep_kernel(const float* __restrict__ e1, const float* __restrict__ e2,
                             const float* __restrict__ gi, const float* __restrict__ gl,
                             const float* __restrict__ go, const float* __restrict__ pj,
                             ushort_t* __restrict__ hi, ushort_t* __restrict__ lo,
                             ushort_t* __restrict__ xah, ushort_t* __restrict__ xal,
                             ushort_t* __restrict__ xbh, ushort_t* __restrict__ xbl) {
    int i = blockIdx.x * 256 + threadIdx.x;
    if (i >= 491520) {
        // tail block: zero the 8 row-major pad rows of both ping-pong X pairs
        int t = threadIdx.x;
        #pragma unroll
        for (int k = 0; k < 8; ++k) {
            size_t off = (size_t)NNODES * 256 + (size_t)k * 256 + t;
            xah[off] = 0; xal[off] = 0; xbh[off] = 0; xbl[off] = 0;
        }
        return;
    }
    float v;
    if (i < 131072)      v = (i < 65536) ? e1[i] : e2[i - 65536];
    else if (i < 196608) v = gi[i - 131072];
    else if (i < 393216) v = gl[i - 196608];
    else if (i < 458752) v = go[i - 393216];
    else                 v = pj[i - 458752];
    int base = (i < 458752) ? (i & ~65535) : 458752;
    int r = i - base;
    int col = r >> 8, k = r & 255;
    int ct = col >> 4, fr = col & 15;
    int c = k >> 5, fq = (k >> 3) & 3, j = k & 7;
    int o = base + (ct * 8 + c) * 512 + (fq * 16 + fr) * 8 + j;
    ushort_t h = f2bf(v);
    hi[o] = h;
    lo[o] = f2bf(v - bf2f(h));
}

// ---------------- gather accumulate helpers ----------------
__device__ __forceinline__ void acc_u4(uint4 u, float* a) {
    const uint32 HM = 0xFFFF0000u;
    a[0] += __uint_as_float(u.x << 16);
    a[1] += __uint_as_float(u.x & HM);
    a[2] += __uint_as_float(u.y << 16);
    a[3] += __uint_as_float(u.y & HM);
    a[4] += __uint_as_float(u.z << 16);
    a[5] += __uint_as_float(u.z & HM);
    a[6] += __uint_as_float(u.w << 16);
    a[7] += __uint_as_float(u.w & HM);
}

// combine self (hi+lo) + dv*acc over 8 cols, split back into bf16 hi/lo octets
__device__ __forceinline__ void pack_pair(uint4 uh, uint4 ul, const float* a, float dv,
                                          short8_t& oh, short8_t& ol) {
    const uint32 HM = 0xFFFF0000u;
    uint32 hu[4] = {uh.x, uh.y, uh.z, uh.w};
    uint32 lu[4] = {ul.x, ul.y, ul.z, ul.w};
    #pragma unroll
    for (int q = 0; q < 4; ++q) {
        float xlo = __uint_as_float(hu[q] << 16) + __uint_as_float(lu[q] << 16);
        float xhi = __uint_as_float(hu[q] & HM) + __uint_as_float(lu[q] & HM);
        float s0 = xlo + dv * a[2 * q];
        float s1 = xhi + dv * a[2 * q + 1];
        ushort_t p0 = f2bf(s0), p1 = f2bf(s1);
        oh[2 * q]     = (short)p0;
        oh[2 * q + 1] = (short)p1;
        ol[2 * q]     = (short)f2bf(s0 - bf2f(p0));
        ol[2 * q + 1] = (short)f2bf(s1 - bf2f(p1));
    }
}

// ---------------- band-GEMM machinery (frag-swizzled A in LDS, B from L2) ----
template<int NTW>
__device__ __forceinline__ void band_step(
        const ushort_t* Ah, const ushort_t* Al,
        const ushort_t* __restrict__ Wh, const ushort_t* __restrict__ Wl,
        int w, int lane, f32x4 (&acc)[2][NTW]) {
    int ct0 = w * NTW;
    short8_t bh[NTW], bl[NTW];
    #pragma unroll
    for (int nt = 0; nt < NTW; ++nt) {
        size_t bo = (size_t)((ct0 + nt) * 8) * 512 + lane * 8;
        bh[nt] = *(const short8_t*)&Wh[bo];
        bl[nt] = *(const short8_t*)&Wl[bo];
    }
    #pragma unroll
    for (int c = 0; c < 8; ++c) {
        short8_t bhn[NTW], bln[NTW];
        if (c < 7) {
            #pragma unroll
            for (int nt = 0; nt < NTW; ++nt) {
                size_t bo = (size_t)((ct0 + nt) * 8 + c + 1) * 512 + lane * 8;
                bhn[nt] = *(const short8_t*)&Wh[bo];
                bln[nt] = *(const short8_t*)&Wl[bo];
            }
        }
        short8_t ah[2], al[2];
        #pragma unroll
        for (int mt = 0; mt < 2; ++mt) {
            int ao = (c * 2 + mt) * LDB + lane * 8;
            ah[mt] = *(const short8_t*)&Ah[ao];
            al[mt] = *(const short8_t*)&Al[ao];
        }
        #pragma unroll
        for (int mt = 0; mt < 2; ++mt)
            #pragma unroll
            for (int nt = 0; nt < NTW; ++nt) {
                f32x4 a = acc[mt][nt];
                a = __builtin_amdgcn_mfma_f32_16x16x32_bf16(ah[mt], bh[nt], a, 0, 0, 0);
                a = __builtin_amdgcn_mfma_f32_16x16x32_bf16(ah[mt], bl[nt], a, 0, 0, 0);
                a = __builtin_amdgcn_mfma_f32_16x16x32_bf16(al[mt], bh[nt], a, 0, 0, 0);
                acc[mt][nt] = a;
            }
        if (c < 7) {
            #pragma unroll
            for (int nt = 0; nt < NTW; ++nt) { bh[nt] = bhn[nt]; bl[nt] = bln[nt]; }
        }
    }
}

template<int NTW>
__device__ __forceinline__ void acc_zero(f32x4 (&acc)[2][NTW]) {
    #pragma unroll
    for (int a = 0; a < 2; ++a)
        #pragma unroll
        for (int b = 0; b < NTW; ++b) {
            f32x4 z = {0.f, 0.f, 0.f, 0.f};
            acc[a][b] = z;
        }
}

// bias + optional relu, split to hi/lo, store in FRAG layout for next step
template<int NTW, bool RELU>
__device__ __forceinline__ void acc_to_lds(
        f32x4 (&acc)[2][NTW], const float* __restrict__ bias,
        int w, int lane, ushort_t* Ah, ushort_t* Al) {
    int fr = lane & 15, fq = lane >> 4;
    int col0 = w * (16 * NTW);
    #pragma unroll
    for (int mt = 0; mt < 2; ++mt)
        #pragma unroll
        for (int nt = 0; nt < NTW; ++nt) {
            int col = col0 + 16 * nt + fr;         // next-step k index
            float bb = bias[col];
            int c = col >> 5, k32 = col & 31;
            int fqn = k32 >> 3, jn = k32 & 7;
            #pragma unroll
            for (int e = 0; e < 4; ++e) {
                int r = 16 * mt + fq * 4 + e;      // 0..31
                float v = acc[mt][nt][e] + bb;
                if (RELU) v = fmaxf(v, 0.0f);
                ushort_t h = f2bf(v);
                int addr = ((c * 2) + (r >> 4)) * LDB + (fqn * 16 + (r & 15)) * 8 + jn;
                Ah[addr] = h;
                Al[addr] = f2bf(v - bf2f(h));
            }
        }
}

// stage a pre-split bf16 pair band [N][256] (row-major) into FRAG LDS
__device__ __forceinline__ void stage_pair(
        const ushort_t* __restrict__ Xh_, const ushort_t* __restrict__ Xl_,
        int row0, int tid, ushort_t* Ah, ushort_t* Al) {
    #pragma unroll
    for (int i = 0; i < 2; ++i) {
        int s = i * 512 + tid;             // 1024 short8 slots
        int r = s >> 5;                    // row 0..31
        int kq = s & 31;                   // k-octet
        short8_t vh = *(const short8_t*)&Xh_[(size_t)(row0 + r) * 256 + kq * 8];
        short8_t vl = *(const short8_t*)&Xl_[(size_t)(row0 + r) * 256 + kq * 8];
        int c = kq >> 2, fq = kq & 3;
        int addr = (c * 2 + (r >> 4)) * LDB + (fq * 16 + (r & 15)) * 8;
        *(short8_t*)&Ah[addr] = vh;
        *(short8_t*)&Al[addr] = vl;
    }
}

// ---------------- fused encoder: nf -> enc1(relu) -> enc2 -> gin(relu) -> X0 ----
__global__ __launch_bounds__(512) void fused_enc_kernel(
        const float* __restrict__ nf,
        const ushort_t* __restrict__ Wh, const ushort_t* __restrict__ Wl,
        const float* __restrict__ b1, const float* __restrict__ b2,
        const float* __restrict__ b3,
        ushort_t* __restrict__ xh, ushort_t* __restrict__ xl) {
    __shared__ __align__(16) ushort_t Ah[16 * LDB];
    __shared__ __align__(16) ushort_t Al[16 * LDB];
    int tid = threadIdx.x;
    int lane = tid & 63;
    int w = __builtin_amdgcn_readfirstlane(tid >> 6);   // 0..7
    int row0 = blockIdx.x * 32;
    int fr = lane & 15, fq = lane >> 4;

    // stage nf band with on-the-fly hi/lo split into frag layout
    #pragma unroll
    for (int i = 0; i < 4; ++i) {
        int s = i * 512 + tid;             // 2048 float4 slots
        int r = s >> 6, k4 = s & 63;
        float4 v = *(const float4*)&nf[(size_t)(row0 + r) * 256 + k4 * 4];
        ushort_t h0 = f2bf(v.x), h1 = f2bf(v.y), h2 = f2bf(v.z), h3 = f2bf(v.w);
        int kq = k4 >> 1, half = (k4 & 1) * 4;
        int c = kq >> 2, fqs = kq & 3;
        int addr = (c * 2 + (r >> 4)) * LDB + (fqs * 16 + (r & 15)) * 8 + half;
        *(ushort4*)&Ah[addr] = make_ushort4(h0, h1, h2, h3);
        *(ushort4*)&Al[addr] =
            make_ushort4(f2bf(v.x - bf2f(h0)), f2bf(v.y - bf2f(h1)),
                         f2bf(v.z - bf2f(h2)), f2bf(v.w - bf2f(h3)));
    }
    __syncthreads();

    f32x4 acc[2][2];
    // enc1 (relu)
    acc_zero<2>(acc);
    band_step<2>(Ah, Al, Wh, Wl, w, lane, acc);
    __syncthreads();
    acc_to_lds<2, true>(acc, b1, w, lane, Ah, Al);
    __syncthreads();
    // enc2 (no relu)
    acc_zero<2>(acc);
    band_step<2>(Ah, Al, Wh + 65536, Wl + 65536, w, lane, acc);
    __syncthreads();
    acc_to_lds<2, false>(acc, b2, w, lane, Ah, Al);
    __syncthreads();
    // gin (relu) -> row-major bf16 pair X0
    acc_zero<2>(acc);
    band_step<2>(Ah, Al, Wh + 131072, Wl + 131072, w, lane, acc);
    int col0 = w * 32;
    #pragma unroll
    for (int mt = 0; mt < 2; ++mt)
        #pragma unroll
        for (int nt = 0; nt < 2; ++nt) {
            int gc = col0 + 16 * nt + fr;
            float bb = b3[gc];
            #pragma unroll
            for (int e = 0; e < 4; ++e) {
                int gr = row0 + 16 * mt + fq * 4 + e;
                float v = fmaxf(acc[mt][nt][e] + bb, 0.0f);
                size_t off = (size_t)gr * 256 + gc;
                ushort_t h = f2bf(v);
                xh[off] = h;
                xl[off] = f2bf(v - bf2f(h));
            }
        }
}

// ---------------- fused GNN layer: gather(spmm) -> frag LDS -> GEMM -> Y -----
// Gather thread = (row r of 32, cg of 16): owns cols [cg*8, cg*8+8) and
// [128+cg*8, 128+cg*8+8). Per neighbor: two contiguous 16B loads -> every 64B
// line is consumed within ONE instruction (same L1-lookup count as the old
// chunked spmm). Result split hi/lo straight into the MFMA A-frag layout.
__global__ __launch_bounds__(512) void fused_layer_kernel(
        const ushort_t* __restrict__ Xh_, const ushort_t* __restrict__ Xl_,
        const ushort_t* __restrict__ ell, const int* __restrict__ cnt,
        const float* __restrict__ dinv,
        const ushort_t* __restrict__ Wh, const ushort_t* __restrict__ Wl,
        const float* __restrict__ bias,
        ushort_t* __restrict__ Yh, ushort_t* __restrict__ Yl) {
    __shared__ __align__(16) ushort_t Ah[16 * LDB];
    __shared__ __align__(16) ushort_t Al[16 * LDB];
    int tid = threadIdx.x;
    int lane = tid & 63;
    int w = __builtin_amdgcn_readfirstlane(tid >> 6);
    int row0 = blockIdx.x * 32;
    {
        int r = tid >> 4, cg = tid & 15;
        int row = row0 + r;
        int n = cnt[row];
        int np = (n + 7) & ~7;
        const ushort_t* rell = ell + (size_t)row * ELLW;
        const ushort_t* xb = Xh_ + cg * 8;
        float a[16] = {};
        for (int i = 0; i < np; i += 8) {
            ushort4 ja = *(const ushort4*)&rell[i];
            ushort4 jb = *(const ushort4*)&rell[i + 4];
            {   // first 4 neighbors: 8 dwordx4 in flight
                uint4 u0 = *(const uint4*)&xb[(size_t)ja.x * 256];
                uint4 v0 = *(const uint4*)&xb[(size_t)ja.x * 256 + 128];
                uint4 u1 = *(const uint4*)&xb[(size_t)ja.y * 256];
                uint4 v1 = *(const uint4*)&xb[(size_t)ja.y * 256 + 128];
                uint4 u2 = *(const uint4*)&xb[(size_t)ja.z * 256];
                uint4 v2 = *(const uint4*)&xb[(size_t)ja.z * 256 + 128];
                uint4 u3 = *(const uint4*)&xb[(size_t)ja.w * 256];
                uint4 v3 = *(const uint4*)&xb[(size_t)ja.w * 256 + 128];
                acc_u4(u0, a); acc_u4(v0, a + 8);
                acc_u4(u1, a); acc_u4(v1, a + 8);
                acc_u4(u2, a); acc_u4(v2, a + 8);
                acc_u4(u3, a); acc_u4(v3, a + 8);
            }
            {   // next 4 neighbors
                uint4 u4 = *(const uint4*)&xb[(size_t)jb.x * 256];
                uint4 v4 = *(const uint4*)&xb[(size_t)jb.x * 256 + 128];
                uint4 u5 = *(const uint4*)&xb[(size_t)jb.y * 256];
                uint4 v5 = *(const uint4*)&xb[(size_t)jb.y * 256 + 128];
                uint4 u6 = *(const uint4*)&xb[(size_t)jb.z * 256];
                uint4 v6 = *(const uint4*)&xb[(size_t)jb.z * 256 + 128];
                uint4 u7 = *(const uint4*)&xb[(size_t)jb.w * 256];
                uint4 v7 = *(const uint4*)&xb[(size_t)jb.w * 256 + 128];
                acc_u4(u4, a); acc_u4(v4, a + 8);
                acc_u4(u5, a); acc_u4(v5, a + 8);
                acc_u4(u6, a); acc_u4(v6, a + 8);
                acc_u4(u7, a); acc_u4(v7, a + 8);
            }
        }
        float dv = dinv[row];
        size_t so = (size_t)row * 256 + cg * 8;
        uint4 h0 = *(const uint4*)&Xh_[so];
        uint4 h1 = *(const uint4*)&Xh_[so + 128];
        uint4 l0 = *(const uint4*)&Xl_[so];
        uint4 l1 = *(const uint4*)&Xl_[so + 128];
        short8_t g0h, g0l, g1h, g1l;
        pack_pair(h0, l0, a, dv, g0h, g0l);
        pack_pair(h1, l1, a + 8, dv, g1h, g1l);
        // frag addr: k = g*128 + cg*8 + j -> c = g*4 + (cg>>2), fq = cg&3, jn = j
        int rh = r >> 4;
        int boff = ((cg & 3) * 16 + (r & 15)) * 8;
        int c0 = cg >> 2;
        *(short8_t*)&Ah[(c0 * 2 + rh) * LDB + boff] = g0h;
        *(short8_t*)&Al[(c0 * 2 + rh) * LDB + boff] = g0l;
        *(short8_t*)&Ah[((4 + c0) * 2 + rh) * LDB + boff] = g1h;
        *(short8_t*)&Al[((4 + c0) * 2 + rh) * LDB + boff] = g1l;
    }
    __syncthreads();
    f32x4 acc[2][2];
    acc_zero<2>(acc);
    band_step<2>(Ah, Al, Wh, Wl, w, lane, acc);
    int fr = lane & 15, fq = lane >> 4;
    int col0 = w * 32;
    #pragma unroll
    for (int mt = 0; mt < 2; ++mt)
        #pragma unroll
        for (int nt = 0; nt < 2; ++nt) {
            int gc = col0 + 16 * nt + fr;
            float bb = bias[gc];
            #pragma unroll
            for (int e = 0; e < 4; ++e) {
                int gr = row0 + 16 * mt + fq * 4 + e;
                float v = fmaxf(acc[mt][nt][e] + bb, 0.0f);   // gl always relu
                size_t off = (size_t)gr * 256 + gc;
                ushort_t h = f2bf(v);
                Yh[off] = h;
                Yl[off] = f2bf(v - bf2f(h));
            }
        }
}

// ---------------- fused output: gout -> proj(relu) -> hc1(relu) -> hc2 + mean ---
__global__ __launch_bounds__(512) void fused_out_kernel(
        const ushort_t* __restrict__ Xh_, const ushort_t* __restrict__ Xl_,
        const ushort_t* __restrict__ Wh, const ushort_t* __restrict__ Wl,
        const float* __restrict__ gout_b, const float* __restrict__ proj_b,
        const float* __restrict__ hc_w1, const float* __restrict__ hc_b1,
        const float* __restrict__ hc_w2, const float* __restrict__ hc_b2,
        float* __restrict__ ne, float* __restrict__ logits, float* __restrict__ gf) {
    __shared__ __align__(16) char arena[33792 + 16896 + 8704];
    ushort_t* Ah = (ushort_t*)arena;                    // 16640 B (MFMA phases)
    ushort_t* Al = (ushort_t*)(arena + 16640);          // 16640 B (MFMA phases)
    float* WL = (float*)arena;                          // 33792 B (hc1 phase)
    float* Pf = (float*)(arena + 33792);                // 32 x 132 f32
    float* T1 = (float*)(arena + 33792 + 16896);        // 32 x 68 f32
    int tid = threadIdx.x;
    int lane = tid & 63;
    int w = __builtin_amdgcn_readfirstlane(tid >> 6);
    int row0 = blockIdx.x * 32;
    int fr = lane & 15, fq = lane >> 4;
    stage_pair(Xh_, Xl_, row0, tid, Ah, Al);
    __syncthreads();

    // gout (no relu) -> frag LDS pair
    f32x4 acc[2][2];
    acc_zero<2>(acc);
    band_step<2>(Ah, Al, Wh + 393216, Wl + 393216, w, lane, acc);
    __syncthreads();
    acc_to_lds<2, false>(acc, gout_b, w, lane, Ah, Al);
    __syncthreads();

    // proj (relu), Mcols=128: 8 waves x 16 cols
    f32x4 acc2[2][1];
    acc_zero<1>(acc2);
    band_step<1>(Ah, Al, Wh + 458752, Wl + 458752, w, lane, acc2);
    __syncthreads();   // all Ah/Al reads done -> safe to overwrite with WL

    // write proj -> ne + Pf; concurrently stage hc_w1 -> WL (disjoint regions)
    int col0 = w * 16;
    #pragma unroll
    for (int mt = 0; mt < 2; ++mt) {
        int gc = col0 + fr;
        float bb = proj_b[gc];
        #pragma unroll
        for (int e = 0; e < 4; ++e) {
            int r = 16 * mt + fq * 4 + e;
            float v = fmaxf(acc2[mt][0][e] + bb, 0.0f);
            ne[(size_t)(row0 + r) * 128 + gc] = v;
            Pf[r * 132 + gc] = v;
        }
    }
    #pragma unroll
    for (int i = 0; i < 4; ++i) {
        int j4 = i * 512 + tid;            // 2048 float4 slots (64 x 32)
        int m = j4 >> 5, k4 = j4 & 31;
        float4 v = *(const float4*)&hc_w1[(size_t)m * 128 + k4 * 4];
        *(float4*)&WL[m * 132 + k4 * 4] = v;
    }
    __syncthreads();

    // hc1 (relu): 32 rows x 64 cols; thread = (row r, cg); col = jj*16+cg
    {
        int r = tid >> 4, cg = tid & 15;
        float a4[4];
        #pragma unroll
        for (int jj = 0; jj < 4; ++jj) a4[jj] = hc_b1[jj * 16 + cg];
        for (int k4 = 0; k4 < 32; ++k4) {
            float4 x = *(const float4*)&Pf[r * 132 + k4 * 4];
            #pragma unroll
            for (int jj = 0; jj < 4; ++jj) {
                float4 wv = *(const float4*)&WL[(jj * 16 + cg) * 132 + k4 * 4];
                a4[jj] += x.x * wv.x + x.y * wv.y + x.z * wv.z + x.w * wv.w;
            }
        }
        #pragma unroll
        for (int jj = 0; jj < 4; ++jj)
            T1[r * 68 + jj * 16 + cg] = fmaxf(a4[jj], 0.0f);
    }
    __syncthreads();

    // hc2: 32x8 logits
    if (tid < 256) {
        int r = tid >> 3, m = tid & 7;
        float s = hc_b2[m];
        #pragma unroll
        for (int k4 = 0; k4 < 16; ++k4) {
            float4 x = *(const float4*)&T1[r * 68 + k4 * 4];
            float4 wv = *(const float4*)&hc_w2[(size_t)m * 64 + k4 * 4];
            s += x.x * wv.x + x.y * wv.y + x.z * wv.z + x.w * wv.w;
        }
        logits[(size_t)(row0 + r) * 8 + m] = s;
    }

    // column-mean partial of ne band
    if (tid < 128) {
        float s = 0.0f;
        #pragma unroll 4
        for (int r = 0; r < 32; ++r) s += Pf[r * 132 + tid];
        atomicAdd(&gf[tid], s * (1.0f / (float)NNODES));
    }
}

extern "C" void kernel_launch(void* const* d_in, const int* in_sizes, int n_in,
                              void* d_out, int out_size, void* d_ws, size_t ws_size,
                              hipStream_t stream) {
    const int N = NNODES;
    const float* nf     = (const float*)d_in[0];
    const int*   ei     = (const int*)d_in[1];
    const float* enc_w1 = (const float*)d_in[2];
    const float* enc_b1 = (const float*)d_in[3];
    const float* enc_w2 = (const float*)d_in[4];
    const float* enc_b2 = (const float*)d_in[5];
    const float* gin_w  = (const float*)d_in[6];
    const float* gin_b  = (const float*)d_in[7];
    const float* gl_w   = (const float*)d_in[8];
    const float* gl_b   = (const float*)d_in[9];
    const float* gout_w = (const float*)d_in[10];
    const float* gout_b = (const float*)d_in[11];
    const float* proj_w = (const float*)d_in[12];
    const float* proj_b = (const float*)d_in[13];
    const float* hc_w1  = (const float*)d_in[14];
    const float* hc_b1  = (const float*)d_in[15];
    const float* hc_w2  = (const float*)d_in[16];
    const float* hc_b2  = (const float*)d_in[17];
    const int E = in_sizes[1] >> 1;

    // workspace carve (bytes):
    // [0, 37748736): masks M+MT -- dead after ell_fill; then aliased by the
    //   two row-major ping-pong X pairs (each (N+8) x 256 bf16 = 6,295,552 B)
    char* ws = (char*)d_ws;
    u64* M  = (u64*)ws;
    u64* MT = M + (size_t)N * WORDS;
    ushort_t* XAh = (ushort_t*)ws;                              //  6,295,552
    ushort_t* XAl = (ushort_t*)(ws + 6295552);                  //  6,295,552
    ushort_t* XBh = (ushort_t*)(ws + 12591104);                 //  6,295,552
    ushort_t* XBl = (ushort_t*)(ws + 18886656);                 // ends 25,182,208
    ushort_t* ell = (ushort_t*)(ws + 37756928);                 //  6,291,456
    int*      cntb = (int*)(ws + 44048384);
    float*    dinv = (float*)(ws + 44097536);
    ushort_t* Whi  = (ushort_t*)(ws + 44146688);                //    983,040
    ushort_t* Wlo  = (ushort_t*)(ws + 45129728);                //    983,040

    float* ne     = (float*)d_out;                        // [N,128]
    float* logits = ne + (size_t)N * 128;                 // [N,8]
    float* gf     = logits + (size_t)N * 8;               // [128]

    hipMemsetAsync(M, 0, 2 * (size_t)N * WORDS * sizeof(u64), stream);
    hipMemsetAsync(gf, 0, 128 * sizeof(float), stream);

    build_mask_kernel<<<(E + 255) / 256, 256, 0, stream>>>(ei, M, MT, E);
    ell_fill_kernel<<<N / 4, 256, 0, stream>>>(M, MT, ell, cntb, dinv);
    // masks dead from here; X pairs may clobber them. wprep's tail block zeroes
    // the X pad rows (must come after ell_fill for exactly that reason).
    wprep_kernel<<<1921, 256, 0, stream>>>(enc_w1, enc_w2, gin_w, gl_w, gout_w, proj_w,
                                           Whi, Wlo, XAh, XAl, XBh, XBl);

    const int GB = N / 32;   // 384 band blocks (512 threads / 8 waves each)
    // encoder chain fused: nf -> X0 (row-major pair in XA)
    fused_enc_kernel<<<GB, 512, 0, stream>>>(nf, Whi, Wlo, enc_b1, enc_b2, gin_b,
                                             XAh, XAl);

    // 3 GNN layers, each a single fused gather+GEMM kernel, ping-pong XA<->XB
    fused_layer_kernel<<<GB, 512, 0, stream>>>(XAh, XAl, ell, cntb, dinv,
                                               Whi + 196608, Wlo + 196608,
                                               gl_b, XBh, XBl);
    fused_layer_kernel<<<GB, 512, 0, stream>>>(XBh, XBl, ell, cntb, dinv,
                                               Whi + 262144, Wlo + 262144,
                                               gl_b + 256, XAh, XAl);
    fused_layer_kernel<<<GB, 512, 0, stream>>>(XAh, XAl, ell, cntb, dinv,
                                               Whi + 327680, Wlo + 327680,
                                               gl_b + 512, XBh, XBl);

    // output chain fused: XB -> ne, logits, gf
    fused_out_kernel<<<GB, 512, 0, stream>>>(
        XBh, XBl, Whi, Wlo, gout_b, proj_b, hc_w1, hc_b1, hc_w2, hc_b2,
        ne, logits, gf);
}

// Round 2
// 313.802 us; speedup vs baseline: 1.0809x; 1.0305x over previous
//
#include <hip/hip_runtime.h>

typedef unsigned long long u64;
typedef unsigned short ushort_t;
typedef unsigned int uint32;

#define NNODES 12288
#define WORDS 192    // 12288 / 64 bits per row
#define ELLW 256     // max neighbors per row (avg ~64)
#define ZROW NNODES  // zeroed pad row index
#define LDB 520      // LDS A-frag c-block stride in shorts (bank-rotates 4 words/block)

typedef __attribute__((ext_vector_type(8))) short short8_t;   // 8 bf16 (4 VGPRs)
typedef __attribute__((ext_vector_type(4))) float f32x4;      // MFMA C/D frag

// ---- bf16 split helpers (RNE) ----
__device__ __forceinline__ ushort_t f2bf(float f) {
    uint32 u = __float_as_uint(f);
    return (ushort_t)((u + 0x7fffu + ((u >> 16) & 1u)) >> 16);
}
__device__ __forceinline__ float bf2f(ushort_t h) {
    return __uint_as_float(((uint32)h) << 16);
}

// ---------------- adjacency build: bitmask M[s][d], MT[d][s] ----------------
__global__ void build_mask_kernel(const int* __restrict__ ei, u64* __restrict__ M,
                                  u64* __restrict__ MT, int E) {
    int e = blockIdx.x * blockDim.x + threadIdx.x;
    if (e >= E) return;
    int s = ei[e];
    int d = ei[E + e];
    atomicOr(&M[(size_t)s * WORDS + (d >> 6)], 1ull << (d & 63));
    atomicOr(&MT[(size_t)d * WORDS + (s >> 6)], 1ull << (s & 63));
}

// ---------------- bitmask -> u16 ELL (padded to x8 with ZROW) ----------------
__global__ __launch_bounds__(256) void ell_fill_kernel(
        const u64* __restrict__ M, const u64* __restrict__ MT,
        ushort_t* __restrict__ ell, int* __restrict__ cnt, float* __restrict__ dinv) {
    int row = blockIdx.x * 4 + (threadIdx.x >> 6);
    int lane = threadIdx.x & 63;
    const u64* rM  = M  + (size_t)row * WORDS;
    const u64* rMT = MT + (size_t)row * WORDS;
    u64 wm[3], wt[3];
    int pm = 0, pt = 0;
    #pragma unroll
    for (int k = 0; k < 3; ++k) {
        wm[k] = rM[lane + 64 * k];  pm += __popcll(wm[k]);
        wt[k] = rMT[lane + 64 * k]; pt += __popcll(wt[k]);
    }
    int inclM = pm, inclT = pt;
    #pragma unroll
    for (int off = 1; off < 64; off <<= 1) {
        int ym = __shfl_up(inclM, off, 64);
        int yt = __shfl_up(inclT, off, 64);
        if (lane >= off) { inclM += ym; inclT += yt; }
    }
    int exclM = inclM - pm;
    int exclT = inclT - pt;
    int totM = __shfl(inclM, 63, 64);
    int totT = __shfl(inclT, 63, 64);
    ushort_t* out = ell + (size_t)row * ELLW;
    int pos = exclM;
    #pragma unroll
    for (int k = 0; k < 3; ++k) {
        u64 bits = wm[k];
        int base = (lane + 64 * k) << 6;
        while (bits) { out[pos++] = (ushort_t)(base + __builtin_ctzll(bits)); bits &= bits - 1; }
    }
    pos = totM + exclT;
    #pragma unroll
    for (int k = 0; k < 3; ++k) {
        u64 bits = wt[k];
        int base = (lane + 64 * k) << 6;
        while (bits) { out[pos++] = (ushort_t)(base + __builtin_ctzll(bits)); bits &= bits - 1; }
    }
    if (lane == 0) {
        int n = totM + totT;
        int np = (n + 7) & ~7;
        for (int p = n; p < np; ++p) out[p] = (ushort_t)ZROW;
        cnt[row] = n;
        dinv[row] = 1.0f / ((float)n + 1e-8f);
    }
}

// ---------------- weight prep: split + B-FRAGMENT SWIZZLE + X pad clear ------
__global__ void wprep_kernel(const float* __restrict__ e1, const float* __restrict__ e2,
                             const float* __restrict__ gi, const float* __restrict__ gl,
                             const float* __restrict__ go, const float* __restrict__ pj,
                             ushort_t* __restrict__ hi, ushort_t* __restrict__ lo,
                             ushort_t* __restrict__ xah, ushort_t* __restrict__ xal,
                             ushort_t* __restrict__ xbh, ushort_t* __restrict__ xbl) {
    int i = blockIdx.x * 256 + threadIdx.x;
    if (i >= 491520) {
        // tail block: zero the 8 row-major pad rows of both ping-pong X pairs
        int t = threadIdx.x;
        #pragma unroll
        for (int k = 0; k < 8; ++k) {
            size_t off = (size_t)NNODES * 256 + (size_t)k * 256 + t;
            xah[off] = 0; xal[off] = 0; xbh[off] = 0; xbl[off] = 0;
        }
        return;
    }
    float v;
    if (i < 131072)      v = (i < 65536) ? e1[i] : e2[i - 65536];
    else if (i < 196608) v = gi[i - 131072];
    else if (i < 393216) v = gl[i - 196608];
    else if (i < 458752) v = go[i - 393216];
    else                 v = pj[i - 458752];
    int base = (i < 458752) ? (i & ~65535) : 458752;
    int r = i - base;
    int col = r >> 8, k = r & 255;
    int ct = col >> 4, fr = col & 15;
    int c = k >> 5, fq = (k >> 3) & 3, j = k & 7;
    int o = base + (ct * 8 + c) * 512 + (fq * 16 + fr) * 8 + j;
    ushort_t h = f2bf(v);
    hi[o] = h;
    lo[o] = f2bf(v - bf2f(h));
}

// ---------------- gather accumulate helpers ----------------
__device__ __forceinline__ void acc_u4(uint4 u, float* a) {
    const uint32 HM = 0xFFFF0000u;
    a[0] += __uint_as_float(u.x << 16);
    a[1] += __uint_as_float(u.x & HM);
    a[2] += __uint_as_float(u.y << 16);
    a[3] += __uint_as_float(u.y & HM);
    a[4] += __uint_as_float(u.z << 16);
    a[5] += __uint_as_float(u.z & HM);
    a[6] += __uint_as_float(u.w << 16);
    a[7] += __uint_as_float(u.w & HM);
}

// combine self (hi+lo) + dv*acc over 8 cols, split back into bf16 hi/lo octets
__device__ __forceinline__ void pack_pair(uint4 uh, uint4 ul, const float* a, float dv,
                                          short8_t& oh, short8_t& ol) {
    const uint32 HM = 0xFFFF0000u;
    uint32 hu[4] = {uh.x, uh.y, uh.z, uh.w};
    uint32 lu[4] = {ul.x, ul.y, ul.z, ul.w};
    #pragma unroll
    for (int q = 0; q < 4; ++q) {
        float xlo = __uint_as_float(hu[q] << 16) + __uint_as_float(lu[q] << 16);
        float xhi = __uint_as_float(hu[q] & HM) + __uint_as_float(lu[q] & HM);
        float s0 = xlo + dv * a[2 * q];
        float s1 = xhi + dv * a[2 * q + 1];
        ushort_t p0 = f2bf(s0), p1 = f2bf(s1);
        oh[2 * q]     = (short)p0;
        oh[2 * q + 1] = (short)p1;
        ol[2 * q]     = (short)f2bf(s0 - bf2f(p0));
        ol[2 * q + 1] = (short)f2bf(s1 - bf2f(p1));
    }
}

// ---------------- 16-row band-GEMM (frag-swizzled A in LDS, B from L2) -------
// A-frag LDS: 8 c-blocks (k octet-pairs), addr = c*LDB + (fq*16 + r)*8 + j
template<int NTW>
__device__ __forceinline__ void band_step16(
        const ushort_t* Ah, const ushort_t* Al,
        const ushort_t* __restrict__ Wh, const ushort_t* __restrict__ Wl,
        int w, int lane, f32x4 (&acc)[NTW]) {
    int ct0 = w * NTW;
    short8_t bh[NTW], bl[NTW];
    #pragma unroll
    for (int nt = 0; nt < NTW; ++nt) {
        size_t bo = (size_t)((ct0 + nt) * 8) * 512 + lane * 8;
        bh[nt] = *(const short8_t*)&Wh[bo];
        bl[nt] = *(const short8_t*)&Wl[bo];
    }
    #pragma unroll
    for (int c = 0; c < 8; ++c) {
        short8_t bhn[NTW], bln[NTW];
        if (c < 7) {
            #pragma unroll
            for (int nt = 0; nt < NTW; ++nt) {
                size_t bo = (size_t)((ct0 + nt) * 8 + c + 1) * 512 + lane * 8;
                bhn[nt] = *(const short8_t*)&Wh[bo];
                bln[nt] = *(const short8_t*)&Wl[bo];
            }
        }
        short8_t ah = *(const short8_t*)&Ah[c * LDB + lane * 8];
        short8_t al = *(const short8_t*)&Al[c * LDB + lane * 8];
        #pragma unroll
        for (int nt = 0; nt < NTW; ++nt) {
            f32x4 a = acc[nt];
            a = __builtin_amdgcn_mfma_f32_16x16x32_bf16(ah, bh[nt], a, 0, 0, 0);
            a = __builtin_amdgcn_mfma_f32_16x16x32_bf16(ah, bl[nt], a, 0, 0, 0);
            a = __builtin_amdgcn_mfma_f32_16x16x32_bf16(al, bh[nt], a, 0, 0, 0);
            acc[nt] = a;
        }
        if (c < 7) {
            #pragma unroll
            for (int nt = 0; nt < NTW; ++nt) { bh[nt] = bhn[nt]; bl[nt] = bln[nt]; }
        }
    }
}

template<int NTW>
__device__ __forceinline__ void acc_zero16(f32x4 (&acc)[NTW]) {
    #pragma unroll
    for (int b = 0; b < NTW; ++b) {
        f32x4 z = {0.f, 0.f, 0.f, 0.f};
        acc[b] = z;
    }
}

// bias + optional relu, split to hi/lo, store in FRAG layout for next step
template<int NTW, bool RELU>
__device__ __forceinline__ void acc_to_lds16(
        f32x4 (&acc)[NTW], const float* __restrict__ bias,
        int w, int lane, ushort_t* Ah, ushort_t* Al) {
    int fr = lane & 15, fq = lane >> 4;
    int col0 = w * (16 * NTW);
    #pragma unroll
    for (int nt = 0; nt < NTW; ++nt) {
        int col = col0 + 16 * nt + fr;         // next-step k index
        float bb = bias[col];
        int c = col >> 5, fqn = (col >> 3) & 3, jn = col & 7;
        #pragma unroll
        for (int e = 0; e < 4; ++e) {
            int r = fq * 4 + e;                // 0..15
            float v = acc[nt][e] + bb;
            if (RELU) v = fmaxf(v, 0.0f);
            ushort_t h = f2bf(v);
            int addr = c * LDB + (fqn * 16 + r) * 8 + jn;
            Ah[addr] = h;
            Al[addr] = f2bf(v - bf2f(h));
        }
    }
}

// stage a pre-split bf16 pair band [N][256] (row-major, 16 rows) into FRAG LDS
__device__ __forceinline__ void stage_pair16(
        const ushort_t* __restrict__ Xh_, const ushort_t* __restrict__ Xl_,
        int row0, int tid, ushort_t* Ah, ushort_t* Al) {
    int r = tid >> 5;                      // row 0..15
    int kq = tid & 31;                     // k-octet
    short8_t vh = *(const short8_t*)&Xh_[(size_t)(row0 + r) * 256 + kq * 8];
    short8_t vl = *(const short8_t*)&Xl_[(size_t)(row0 + r) * 256 + kq * 8];
    int c = kq >> 2, fq = kq & 3;
    int addr = c * LDB + (fq * 16 + r) * 8;
    *(short8_t*)&Ah[addr] = vh;
    *(short8_t*)&Al[addr] = vl;
}

// ---------------- fused encoder: nf -> enc1(relu) -> enc2 -> gin(relu) -> X0 ----
__global__ __launch_bounds__(512) void fused_enc_kernel(
        const float* __restrict__ nf,
        const ushort_t* __restrict__ Wh, const ushort_t* __restrict__ Wl,
        const float* __restrict__ b1, const float* __restrict__ b2,
        const float* __restrict__ b3,
        ushort_t* __restrict__ xh, ushort_t* __restrict__ xl) {
    __shared__ __align__(16) ushort_t Ah[8 * LDB];
    __shared__ __align__(16) ushort_t Al[8 * LDB];
    int tid = threadIdx.x;
    int lane = tid & 63;
    int w = __builtin_amdgcn_readfirstlane(tid >> 6);   // 0..7
    int row0 = blockIdx.x * 16;
    int fr = lane & 15, fq = lane >> 4;

    // stage nf band (16 rows x 64 float4) with on-the-fly hi/lo split
    #pragma unroll
    for (int i = 0; i < 2; ++i) {
        int s = i * 512 + tid;             // 1024 float4 slots
        int r = s >> 6, k4 = s & 63;
        float4 v = *(const float4*)&nf[(size_t)(row0 + r) * 256 + k4 * 4];
        ushort_t h0 = f2bf(v.x), h1 = f2bf(v.y), h2 = f2bf(v.z), h3 = f2bf(v.w);
        int kq = k4 >> 1, half = (k4 & 1) * 4;
        int c = kq >> 2, fqs = kq & 3;
        int addr = c * LDB + (fqs * 16 + r) * 8 + half;
        *(ushort4*)&Ah[addr] = make_ushort4(h0, h1, h2, h3);
        *(ushort4*)&Al[addr] =
            make_ushort4(f2bf(v.x - bf2f(h0)), f2bf(v.y - bf2f(h1)),
                         f2bf(v.z - bf2f(h2)), f2bf(v.w - bf2f(h3)));
    }
    __syncthreads();

    f32x4 acc[2];
    // enc1 (relu)
    acc_zero16<2>(acc);
    band_step16<2>(Ah, Al, Wh, Wl, w, lane, acc);
    __syncthreads();
    acc_to_lds16<2, true>(acc, b1, w, lane, Ah, Al);
    __syncthreads();
    // enc2 (no relu)
    acc_zero16<2>(acc);
    band_step16<2>(Ah, Al, Wh + 65536, Wl + 65536, w, lane, acc);
    __syncthreads();
    acc_to_lds16<2, false>(acc, b2, w, lane, Ah, Al);
    __syncthreads();
    // gin (relu) -> row-major bf16 pair X0
    acc_zero16<2>(acc);
    band_step16<2>(Ah, Al, Wh + 131072, Wl + 131072, w, lane, acc);
    int col0 = w * 32;
    #pragma unroll
    for (int nt = 0; nt < 2; ++nt) {
        int gc = col0 + 16 * nt + fr;
        float bb = b3[gc];
        #pragma unroll
        for (int e = 0; e < 4; ++e) {
            int gr = row0 + fq * 4 + e;
            float v = fmaxf(acc[nt][e] + bb, 0.0f);
            size_t off = (size_t)gr * 256 + gc;
            ushort_t h = f2bf(v);
            xh[off] = h;
            xl[off] = f2bf(v - bf2f(h));
        }
    }
}

// ---------------- fused GNN layer: gather(spmm) -> frag LDS -> GEMM -> Y -----
// 16-row band, 768 blocks (exactly 3/CU, whole grid co-resident).
// Gather thread = (row r = tid>>5, cg = tid&31): owns cols [cg*8, cg*8+8).
// Per 8-neighbor iteration: 8 independent dwordx4 loads; a wave's lanes cover
// 2 neighbor rows x 512B contiguous -> 16 L1 lines/instr, 2 segments.
__global__ __launch_bounds__(512) void fused_layer_kernel(
        const ushort_t* __restrict__ Xh_, const ushort_t* __restrict__ Xl_,
        const ushort_t* __restrict__ ell, const int* __restrict__ cnt,
        const float* __restrict__ dinv,
        const ushort_t* __restrict__ Wh, const ushort_t* __restrict__ Wl,
        const float* __restrict__ bias,
        ushort_t* __restrict__ Yh, ushort_t* __restrict__ Yl) {
    __shared__ __align__(16) ushort_t Ah[8 * LDB];
    __shared__ __align__(16) ushort_t Al[8 * LDB];
    int tid = threadIdx.x;
    int lane = tid & 63;
    int w = __builtin_amdgcn_readfirstlane(tid >> 6);
    int row0 = blockIdx.x * 16;
    {
        int r = tid >> 5, cg = tid & 31;
        int row = row0 + r;
        int n = cnt[row];
        int np = (n + 7) & ~7;
        const ushort_t* rell = ell + (size_t)row * ELLW;
        const ushort_t* xb = Xh_ + cg * 8;
        float a[8] = {};
        for (int i = 0; i < np; i += 8) {
            ushort4 ja = *(const ushort4*)&rell[i];
            ushort4 jb = *(const ushort4*)&rell[i + 4];
            uint4 u0 = *(const uint4*)&xb[(size_t)ja.x * 256];
            uint4 u1 = *(const uint4*)&xb[(size_t)ja.y * 256];
            uint4 u2 = *(const uint4*)&xb[(size_t)ja.z * 256];
            uint4 u3 = *(const uint4*)&xb[(size_t)ja.w * 256];
            uint4 u4 = *(const uint4*)&xb[(size_t)jb.x * 256];
            uint4 u5 = *(const uint4*)&xb[(size_t)jb.y * 256];
            uint4 u6 = *(const uint4*)&xb[(size_t)jb.z * 256];
            uint4 u7 = *(const uint4*)&xb[(size_t)jb.w * 256];
            acc_u4(u0, a); acc_u4(u1, a); acc_u4(u2, a); acc_u4(u3, a);
            acc_u4(u4, a); acc_u4(u5, a); acc_u4(u6, a); acc_u4(u7, a);
        }
        float dv = dinv[row];
        size_t so = (size_t)row * 256 + cg * 8;
        uint4 h0 = *(const uint4*)&Xh_[so];
        uint4 l0 = *(const uint4*)&Xl_[so];
        short8_t gh, gl;
        pack_pair(h0, l0, a, dv, gh, gl);
        // frag addr: k = cg*8 + j -> c = cg>>2, fq = cg&3, jn = j
        int addr = (cg >> 2) * LDB + ((cg & 3) * 16 + r) * 8;
        *(short8_t*)&Ah[addr] = gh;
        *(short8_t*)&Al[addr] = gl;
    }
    __syncthreads();
    f32x4 acc[2];
    acc_zero16<2>(acc);
    band_step16<2>(Ah, Al, Wh, Wl, w, lane, acc);
    int fr = lane & 15, fq = lane >> 4;
    int col0 = w * 32;
    #pragma unroll
    for (int nt = 0; nt < 2; ++nt) {
        int gc = col0 + 16 * nt + fr;
        float bb = bias[gc];
        #pragma unroll
        for (int e = 0; e < 4; ++e) {
            int gr = row0 + fq * 4 + e;
            float v = fmaxf(acc[nt][e] + bb, 0.0f);   // gl always relu
            size_t off = (size_t)gr * 256 + gc;
            ushort_t h = f2bf(v);
            Yh[off] = h;
            Yl[off] = f2bf(v - bf2f(h));
        }
    }
}

// ---------------- fused output: gout -> proj(relu) -> hc1(relu) -> hc2 + mean ---
__global__ __launch_bounds__(512) void fused_out_kernel(
        const ushort_t* __restrict__ Xh_, const ushort_t* __restrict__ Xl_,
        const ushort_t* __restrict__ Wh, const ushort_t* __restrict__ Wl,
        const float* __restrict__ gout_b, const float* __restrict__ proj_b,
        const float* __restrict__ hc_w1, const float* __restrict__ hc_b1,
        const float* __restrict__ hc_w2, const float* __restrict__ hc_b2,
        float* __restrict__ ne, float* __restrict__ logits, float* __restrict__ gf) {
    __shared__ __align__(16) char arena[33792 + 8448 + 4352];
    ushort_t* Ah = (ushort_t*)arena;                    // 8320 B (MFMA phases)
    ushort_t* Al = (ushort_t*)(arena + 8320);           // 8320 B (MFMA phases)
    float* WL = (float*)arena;                          // 33792 B (hc1 phase), aliases Ah/Al
    float* Pf = (float*)(arena + 33792);                // 16 x 132 f32
    float* T1 = (float*)(arena + 33792 + 8448);         // 16 x 68 f32
    int tid = threadIdx.x;
    int lane = tid & 63;
    int w = __builtin_amdgcn_readfirstlane(tid >> 6);
    int row0 = blockIdx.x * 16;
    int fr = lane & 15, fq = lane >> 4;
    stage_pair16(Xh_, Xl_, row0, tid, Ah, Al);
    __syncthreads();

    // gout (no relu) -> frag LDS pair
    f32x4 acc[2];
    acc_zero16<2>(acc);
    band_step16<2>(Ah, Al, Wh + 393216, Wl + 393216, w, lane, acc);
    __syncthreads();
    acc_to_lds16<2, false>(acc, gout_b, w, lane, Ah, Al);
    __syncthreads();

    // proj (relu), Mcols=128: 8 waves x 16 cols
    f32x4 acc2[1];
    acc_zero16<1>(acc2);
    band_step16<1>(Ah, Al, Wh + 458752, Wl + 458752, w, lane, acc2);
    __syncthreads();   // all Ah/Al reads done -> safe to overwrite with WL

    // write proj -> ne + Pf; concurrently stage hc_w1 -> WL (disjoint regions)
    {
        int gc = w * 16 + fr;
        float bb = proj_b[gc];
        #pragma unroll
        for (int e = 0; e < 4; ++e) {
            int r = fq * 4 + e;
            float v = fmaxf(acc2[0][e] + bb, 0.0f);
            ne[(size_t)(row0 + r) * 128 + gc] = v;
            Pf[r * 132 + gc] = v;
        }
    }
    #pragma unroll
    for (int i = 0; i < 4; ++i) {
        int j4 = i * 512 + tid;            // 2048 float4 slots (64 x 32)
        int m = j4 >> 5, k4 = j4 & 31;
        float4 v = *(const float4*)&hc_w1[(size_t)m * 128 + k4 * 4];
        *(float4*)&WL[m * 132 + k4 * 4] = v;
    }
    __syncthreads();

    // hc1 (relu): 16 rows x 64 cols; thread = (row r, cg of 32); col = jj*32+cg
    {
        int r = tid >> 5, cg = tid & 31;
        float a2[2];
        #pragma unroll
        for (int jj = 0; jj < 2; ++jj) a2[jj] = hc_b1[jj * 32 + cg];
        for (int k4 = 0; k4 < 32; ++k4) {
            float4 x = *(const float4*)&Pf[r * 132 + k4 * 4];
            #pragma unroll
            for (int jj = 0; jj < 2; ++jj) {
                float4 wv = *(const float4*)&WL[(jj * 32 + cg) * 132 + k4 * 4];
                a2[jj] += x.x * wv.x + x.y * wv.y + x.z * wv.z + x.w * wv.w;
            }
        }
        #pragma unroll
        for (int jj = 0; jj < 2; ++jj)
            T1[r * 68 + jj * 32 + cg] = fmaxf(a2[jj], 0.0f);
    }
    __syncthreads();

    // hc2: 16x8 logits
    if (tid < 128) {
        int r = tid >> 3, m = tid & 7;
        float s = hc_b2[m];
        #pragma unroll
        for (int k4 = 0; k4 < 16; ++k4) {
            float4 x = *(const float4*)&T1[r * 68 + k4 * 4];
            float4 wv = *(const float4*)&hc_w2[(size_t)m * 64 + k4 * 4];
            s += x.x * wv.x + x.y * wv.y + x.z * wv.z + x.w * wv.w;
        }
        logits[(size_t)(row0 + r) * 8 + m] = s;
    }

    // column-mean partial of ne band
    if (tid >= 128 && tid < 256) {
        int col = tid - 128;
        float s = 0.0f;
        #pragma unroll 4
        for (int r = 0; r < 16; ++r) s += Pf[r * 132 + col];
        atomicAdd(&gf[col], s * (1.0f / (float)NNODES));
    }
}

extern "C" void kernel_launch(void* const* d_in, const int* in_sizes, int n_in,
                              void* d_out, int out_size, void* d_ws, size_t ws_size,
                              hipStream_t stream) {
    const int N = NNODES;
    const float* nf     = (const float*)d_in[0];
    const int*   ei     = (const int*)d_in[1];
    const float* enc_w1 = (const float*)d_in[2];
    const float* enc_b1 = (const float*)d_in[3];
    const float* enc_w2 = (const float*)d_in[4];
    const float* enc_b2 = (const float*)d_in[5];
    const float* gin_w  = (const float*)d_in[6];
    const float* gin_b  = (const float*)d_in[7];
    const float* gl_w   = (const float*)d_in[8];
    const float* gl_b   = (const float*)d_in[9];
    const float* gout_w = (const float*)d_in[10];
    const float* gout_b = (const float*)d_in[11];
    const float* proj_w = (const float*)d_in[12];
    const float* proj_b = (const float*)d_in[13];
    const float* hc_w1  = (const float*)d_in[14];
    const float* hc_b1  = (const float*)d_in[15];
    const float* hc_w2  = (const float*)d_in[16];
    const float* hc_b2  = (const float*)d_in[17];
    const int E = in_sizes[1] >> 1;

    // workspace carve (bytes):
    // [0, 37748736): masks M+MT -- dead after ell_fill; then aliased by the
    //   two row-major ping-pong X pairs (each (N+8) x 256 bf16 = 6,295,552 B)
    char* ws = (char*)d_ws;
    u64* M  = (u64*)ws;
    u64* MT = M + (size_t)N * WORDS;
    ushort_t* XAh = (ushort_t*)ws;                              //  6,295,552
    ushort_t* XAl = (ushort_t*)(ws + 6295552);                  //  6,295,552
    ushort_t* XBh = (ushort_t*)(ws + 12591104);                 //  6,295,552
    ushort_t* XBl = (ushort_t*)(ws + 18886656);                 // ends 25,182,208
    ushort_t* ell = (ushort_t*)(ws + 37756928);                 //  6,291,456
    int*      cntb = (int*)(ws + 44048384);
    float*    dinv = (float*)(ws + 44097536);
    ushort_t* Whi  = (ushort_t*)(ws + 44146688);                //    983,040
    ushort_t* Wlo  = (ushort_t*)(ws + 45129728);                //    983,040

    float* ne     = (float*)d_out;                        // [N,128]
    float* logits = ne + (size_t)N * 128;                 // [N,8]
    float* gf     = logits + (size_t)N * 8;               // [128]

    hipMemsetAsync(M, 0, 2 * (size_t)N * WORDS * sizeof(u64), stream);
    hipMemsetAsync(gf, 0, 128 * sizeof(float), stream);

    build_mask_kernel<<<(E + 255) / 256, 256, 0, stream>>>(ei, M, MT, E);
    ell_fill_kernel<<<N / 4, 256, 0, stream>>>(M, MT, ell, cntb, dinv);
    // masks dead from here; X pairs may clobber them. wprep's tail block zeroes
    // the X pad rows (must come after ell_fill for exactly that reason).
    wprep_kernel<<<1921, 256, 0, stream>>>(enc_w1, enc_w2, gin_w, gl_w, gout_w, proj_w,
                                           Whi, Wlo, XAh, XAl, XBh, XBl);

    const int GB = N / 16;   // 768 band blocks = exactly 3 per CU
    // encoder chain fused: nf -> X0 (row-major pair in XA)
    fused_enc_kernel<<<GB, 512, 0, stream>>>(nf, Whi, Wlo, enc_b1, enc_b2, gin_b,
                                             XAh, XAl);

    // 3 GNN layers, each a single fused gather+GEMM kernel, ping-pong XA<->XB
    fused_layer_kernel<<<GB, 512, 0, stream>>>(XAh, XAl, ell, cntb, dinv,
                                               Whi + 196608, Wlo + 196608,
                                               gl_b, XBh, XBl);
    fused_layer_kernel<<<GB, 512, 0, stream>>>(XBh, XBl, ell, cntb, dinv,
                                               Whi + 262144, Wlo + 262144,
                                               gl_b + 256, XAh, XAl);
    fused_layer_kernel<<<GB, 512, 0, stream>>>(XAh, XAl, ell, cntb, dinv,
                                               Whi + 327680, Wlo + 327680,
                                               gl_b + 512, XBh, XBl);

    // output chain fused: XB -> ne, logits, gf
    fused_out_kernel<<<GB, 512, 0, stream>>>(
        XBh, XBl, Whi, Wlo, gout_b, proj_b, hc_w1, hc_b1, hc_w2, hc_b2,
        ne, logits, gf);
}

// Round 3
// 301.160 us; speedup vs baseline: 1.1262x; 1.0420x over previous
//
#include <hip/hip_runtime.h>

typedef unsigned long long u64;
typedef unsigned short ushort_t;
typedef unsigned int uint32;

#define NNODES 12288
#define WORDS 192    // 12288 / 64 bits per row
#define ELLW 256     // max neighbors per row (avg ~64)
#define ZROW NNODES  // zeroed pad row index
#define LDB 520      // LDS A-frag c-block stride in shorts (bank-rotates 4 words/block)

typedef __attribute__((ext_vector_type(8))) short short8_t;   // 8 bf16 (4 VGPRs)
typedef __attribute__((ext_vector_type(4))) float f32x4;      // MFMA C/D frag

// ---- bf16 split helpers (RNE) ----
__device__ __forceinline__ ushort_t f2bf(float f) {
    uint32 u = __float_as_uint(f);
    return (ushort_t)((u + 0x7fffu + ((u >> 16) & 1u)) >> 16);
}
__device__ __forceinline__ float bf2f(ushort_t h) {
    return __uint_as_float(((uint32)h) << 16);
}

// ---------------- K1: build_mask || wprep || X-pad clear ----------------
// blocks [0, nbB): adjacency bitmask build (atomicOr, dedup semantics)
// blocks [nbB, nbB+960): weight split + B-fragment swizzle (exactly 491520 elems)
// block nbB+960: zero the 8 row-major pad rows of both ping-pong X pairs
__global__ __launch_bounds__(512) void prep_kernel(
        const int* __restrict__ ei, int E, int nbB,
        u64* __restrict__ M, u64* __restrict__ MT,
        const float* __restrict__ e1, const float* __restrict__ e2,
        const float* __restrict__ gi, const float* __restrict__ gl,
        const float* __restrict__ go, const float* __restrict__ pj,
        ushort_t* __restrict__ hi, ushort_t* __restrict__ lo,
        ushort_t* __restrict__ xah, ushort_t* __restrict__ xal,
        ushort_t* __restrict__ xbh, ushort_t* __restrict__ xbl) {
    int b = blockIdx.x;
    int t = threadIdx.x;
    if (b < nbB) {
        int e = b * 512 + t;
        if (e >= E) return;
        int s = ei[e];
        int d = ei[E + e];
        atomicOr(&M[(size_t)s * WORDS + (d >> 6)], 1ull << (d & 63));
        atomicOr(&MT[(size_t)d * WORDS + (s >> 6)], 1ull << (s & 63));
        return;
    }
    if (b == nbB + 960) {
        #pragma unroll
        for (int k = 0; k < 4; ++k) {
            size_t off = (size_t)NNODES * 256 + (size_t)k * 512 + t;
            xah[off] = 0; xal[off] = 0; xbh[off] = 0; xbl[off] = 0;
        }
        return;
    }
    int i = (b - nbB) * 512 + t;           // [0, 491520) exactly
    float v;
    if (i < 131072)      v = (i < 65536) ? e1[i] : e2[i - 65536];
    else if (i < 196608) v = gi[i - 131072];
    else if (i < 393216) v = gl[i - 196608];
    else if (i < 458752) v = go[i - 393216];
    else                 v = pj[i - 458752];
    int base = (i < 458752) ? (i & ~65535) : 458752;
    int r = i - base;
    int col = r >> 8, k = r & 255;
    int ct = col >> 4, fr = col & 15;
    int c = k >> 5, fq = (k >> 3) & 3, j = k & 7;
    int o = base + (ct * 8 + c) * 512 + (fq * 16 + fr) * 8 + j;
    ushort_t h = f2bf(v);
    hi[o] = h;
    lo[o] = f2bf(v - bf2f(h));
}

// ---------------- gather accumulate helpers ----------------
__device__ __forceinline__ void acc_u4(uint4 u, float* a) {
    const uint32 HM = 0xFFFF0000u;
    a[0] += __uint_as_float(u.x << 16);
    a[1] += __uint_as_float(u.x & HM);
    a[2] += __uint_as_float(u.y << 16);
    a[3] += __uint_as_float(u.y & HM);
    a[4] += __uint_as_float(u.z << 16);
    a[5] += __uint_as_float(u.z & HM);
    a[6] += __uint_as_float(u.w << 16);
    a[7] += __uint_as_float(u.w & HM);
}

// combine self (hi+lo) + dv*acc over 8 cols, split back into bf16 hi/lo octets
__device__ __forceinline__ void pack_pair(uint4 uh, uint4 ul, const float* a, float dv,
                                          short8_t& oh, short8_t& ol) {
    const uint32 HM = 0xFFFF0000u;
    uint32 hu[4] = {uh.x, uh.y, uh.z, uh.w};
    uint32 lu[4] = {ul.x, ul.y, ul.z, ul.w};
    #pragma unroll
    for (int q = 0; q < 4; ++q) {
        float xlo = __uint_as_float(hu[q] << 16) + __uint_as_float(lu[q] << 16);
        float xhi = __uint_as_float(hu[q] & HM) + __uint_as_float(lu[q] & HM);
        float s0 = xlo + dv * a[2 * q];
        float s1 = xhi + dv * a[2 * q + 1];
        ushort_t p0 = f2bf(s0), p1 = f2bf(s1);
        oh[2 * q]     = (short)p0;
        oh[2 * q + 1] = (short)p1;
        ol[2 * q]     = (short)f2bf(s0 - bf2f(p0));
        ol[2 * q + 1] = (short)f2bf(s1 - bf2f(p1));
    }
}

// ---------------- 16-row band-GEMM (frag-swizzled A in LDS, B from L2) -------
// A-frag LDS: 8 c-blocks (k octet-pairs), addr = c*LDB + (fq*16 + r)*8 + j
template<int NTW>
__device__ __forceinline__ void band_step16(
        const ushort_t* Ah, const ushort_t* Al,
        const ushort_t* __restrict__ Wh, const ushort_t* __restrict__ Wl,
        int w, int lane, f32x4 (&acc)[NTW]) {
    int ct0 = w * NTW;
    short8_t bh[NTW], bl[NTW];
    #pragma unroll
    for (int nt = 0; nt < NTW; ++nt) {
        size_t bo = (size_t)((ct0 + nt) * 8) * 512 + lane * 8;
        bh[nt] = *(const short8_t*)&Wh[bo];
        bl[nt] = *(const short8_t*)&Wl[bo];
    }
    #pragma unroll
    for (int c = 0; c < 8; ++c) {
        short8_t bhn[NTW], bln[NTW];
        if (c < 7) {
            #pragma unroll
            for (int nt = 0; nt < NTW; ++nt) {
                size_t bo = (size_t)((ct0 + nt) * 8 + c + 1) * 512 + lane * 8;
                bhn[nt] = *(const short8_t*)&Wh[bo];
                bln[nt] = *(const short8_t*)&Wl[bo];
            }
        }
        short8_t ah = *(const short8_t*)&Ah[c * LDB + lane * 8];
        short8_t al = *(const short8_t*)&Al[c * LDB + lane * 8];
        #pragma unroll
        for (int nt = 0; nt < NTW; ++nt) {
            f32x4 a = acc[nt];
            a = __builtin_amdgcn_mfma_f32_16x16x32_bf16(ah, bh[nt], a, 0, 0, 0);
            a = __builtin_amdgcn_mfma_f32_16x16x32_bf16(ah, bl[nt], a, 0, 0, 0);
            a = __builtin_amdgcn_mfma_f32_16x16x32_bf16(al, bh[nt], a, 0, 0, 0);
            acc[nt] = a;
        }
        if (c < 7) {
            #pragma unroll
            for (int nt = 0; nt < NTW; ++nt) { bh[nt] = bhn[nt]; bl[nt] = bln[nt]; }
        }
    }
}

template<int NTW>
__device__ __forceinline__ void acc_zero16(f32x4 (&acc)[NTW]) {
    #pragma unroll
    for (int b = 0; b < NTW; ++b) {
        f32x4 z = {0.f, 0.f, 0.f, 0.f};
        acc[b] = z;
    }
}

// bias + optional relu, split to hi/lo, store in FRAG layout for next step
template<int NTW, bool RELU>
__device__ __forceinline__ void acc_to_lds16(
        f32x4 (&acc)[NTW], const float* __restrict__ bias,
        int w, int lane, ushort_t* Ah, ushort_t* Al) {
    int fr = lane & 15, fq = lane >> 4;
    int col0 = w * (16 * NTW);
    #pragma unroll
    for (int nt = 0; nt < NTW; ++nt) {
        int col = col0 + 16 * nt + fr;         // next-step k index
        float bb = bias[col];
        int c = col >> 5, fqn = (col >> 3) & 3, jn = col & 7;
        #pragma unroll
        for (int e = 0; e < 4; ++e) {
            int r = fq * 4 + e;                // 0..15
            float v = acc[nt][e] + bb;
            if (RELU) v = fmaxf(v, 0.0f);
            ushort_t h = f2bf(v);
            int addr = c * LDB + (fqn * 16 + r) * 8 + jn;
            Ah[addr] = h;
            Al[addr] = f2bf(v - bf2f(h));
        }
    }
}

// stage a pre-split bf16 pair band [N][256] (row-major, 16 rows) into FRAG LDS
__device__ __forceinline__ void stage_pair16(
        const ushort_t* __restrict__ Xh_, const ushort_t* __restrict__ Xl_,
        int row0, int tid, ushort_t* Ah, ushort_t* Al) {
    int r = tid >> 5;                      // row 0..15
    int kq = tid & 31;                     // k-octet
    short8_t vh = *(const short8_t*)&Xh_[(size_t)(row0 + r) * 256 + kq * 8];
    short8_t vl = *(const short8_t*)&Xl_[(size_t)(row0 + r) * 256 + kq * 8];
    int c = kq >> 2, fq = kq & 3;
    int addr = c * LDB + (fq * 16 + r) * 8;
    *(short8_t*)&Ah[addr] = vh;
    *(short8_t*)&Al[addr] = vl;
}

// ---------------- K2: fused encoder || ell_fill ----------------
// blocks [0, 768): nf -> enc1(relu) -> enc2 -> gin(relu) -> X0 (16-row bands)
// blocks [768, 2304): bitmask -> u16 ELL, 8 rows per block (wave per row)
__global__ __launch_bounds__(512) void enc_ell_kernel(
        const float* __restrict__ nf,
        const ushort_t* __restrict__ Wh, const ushort_t* __restrict__ Wl,
        const float* __restrict__ b1, const float* __restrict__ b2,
        const float* __restrict__ b3,
        ushort_t* __restrict__ xh, ushort_t* __restrict__ xl,
        const u64* __restrict__ M, const u64* __restrict__ MT,
        ushort_t* __restrict__ ell, int* __restrict__ cnt, float* __restrict__ dinv) {
    __shared__ __align__(16) ushort_t Ah[8 * LDB];
    __shared__ __align__(16) ushort_t Al[8 * LDB];
    int tid = threadIdx.x;
    int lane = tid & 63;
    if (blockIdx.x >= 768) {
        // ---- ell_fill branch: one wave per row ----
        int row = (blockIdx.x - 768) * 8 + (tid >> 6);
        const u64* rM  = M  + (size_t)row * WORDS;
        const u64* rMT = MT + (size_t)row * WORDS;
        u64 wm[3], wt[3];
        int pm = 0, pt = 0;
        #pragma unroll
        for (int k = 0; k < 3; ++k) {
            wm[k] = rM[lane + 64 * k];  pm += __popcll(wm[k]);
            wt[k] = rMT[lane + 64 * k]; pt += __popcll(wt[k]);
        }
        int inclM = pm, inclT = pt;
        #pragma unroll
        for (int off = 1; off < 64; off <<= 1) {
            int ym = __shfl_up(inclM, off, 64);
            int yt = __shfl_up(inclT, off, 64);
            if (lane >= off) { inclM += ym; inclT += yt; }
        }
        int exclM = inclM - pm;
        int exclT = inclT - pt;
        int totM = __shfl(inclM, 63, 64);
        int totT = __shfl(inclT, 63, 64);
        ushort_t* out = ell + (size_t)row * ELLW;
        int pos = exclM;
        #pragma unroll
        for (int k = 0; k < 3; ++k) {
            u64 bits = wm[k];
            int base = (lane + 64 * k) << 6;
            while (bits) { out[pos++] = (ushort_t)(base + __builtin_ctzll(bits)); bits &= bits - 1; }
        }
        pos = totM + exclT;
        #pragma unroll
        for (int k = 0; k < 3; ++k) {
            u64 bits = wt[k];
            int base = (lane + 64 * k) << 6;
            while (bits) { out[pos++] = (ushort_t)(base + __builtin_ctzll(bits)); bits &= bits - 1; }
        }
        if (lane == 0) {
            int n = totM + totT;
            int np = (n + 7) & ~7;
            for (int p = n; p < np; ++p) out[p] = (ushort_t)ZROW;
            cnt[row] = n;
            dinv[row] = 1.0f / ((float)n + 1e-8f);
        }
        return;
    }
    // ---- encoder branch ----
    int w = __builtin_amdgcn_readfirstlane(tid >> 6);   // 0..7
    int row0 = blockIdx.x * 16;
    int fr = lane & 15, fq = lane >> 4;

    // stage nf band (16 rows x 64 float4) with on-the-fly hi/lo split
    #pragma unroll
    for (int i = 0; i < 2; ++i) {
        int s = i * 512 + tid;             // 1024 float4 slots
        int r = s >> 6, k4 = s & 63;
        float4 v = *(const float4*)&nf[(size_t)(row0 + r) * 256 + k4 * 4];
        ushort_t h0 = f2bf(v.x), h1 = f2bf(v.y), h2 = f2bf(v.z), h3 = f2bf(v.w);
        int kq = k4 >> 1, half = (k4 & 1) * 4;
        int c = kq >> 2, fqs = kq & 3;
        int addr = c * LDB + (fqs * 16 + r) * 8 + half;
        *(ushort4*)&Ah[addr] = make_ushort4(h0, h1, h2, h3);
        *(ushort4*)&Al[addr] =
            make_ushort4(f2bf(v.x - bf2f(h0)), f2bf(v.y - bf2f(h1)),
                         f2bf(v.z - bf2f(h2)), f2bf(v.w - bf2f(h3)));
    }
    __syncthreads();

    f32x4 acc[2];
    // enc1 (relu)
    acc_zero16<2>(acc);
    band_step16<2>(Ah, Al, Wh, Wl, w, lane, acc);
    __syncthreads();
    acc_to_lds16<2, true>(acc, b1, w, lane, Ah, Al);
    __syncthreads();
    // enc2 (no relu)
    acc_zero16<2>(acc);
    band_step16<2>(Ah, Al, Wh + 65536, Wl + 65536, w, lane, acc);
    __syncthreads();
    acc_to_lds16<2, false>(acc, b2, w, lane, Ah, Al);
    __syncthreads();
    // gin (relu) -> row-major bf16 pair X0
    acc_zero16<2>(acc);
    band_step16<2>(Ah, Al, Wh + 131072, Wl + 131072, w, lane, acc);
    int col0 = w * 32;
    #pragma unroll
    for (int nt = 0; nt < 2; ++nt) {
        int gc = col0 + 16 * nt + fr;
        float bb = b3[gc];
        #pragma unroll
        for (int e = 0; e < 4; ++e) {
            int gr = row0 + fq * 4 + e;
            float v = fmaxf(acc[nt][e] + bb, 0.0f);
            size_t off = (size_t)gr * 256 + gc;
            ushort_t h = f2bf(v);
            xh[off] = h;
            xl[off] = f2bf(v - bf2f(h));
        }
    }
}

// ---------------- fused GNN layer: gather(spmm) -> frag LDS -> GEMM -> Y -----
// 16-row band, 768 blocks. __launch_bounds__(512, 8) pins VGPR <= 64 so the
// whole grid is co-resident (VGPR quantization: 72 VGPR would land in the
// 128-class = 16 waves/CU). Gather keeps 4 loads in flight (16 data VGPRs).
// Accumulate order u0->u3 per quad preserved -> bitwise-identical results.
__global__ __launch_bounds__(512, 8) void fused_layer_kernel(
        const ushort_t* __restrict__ Xh_, const ushort_t* __restrict__ Xl_,
        const ushort_t* __restrict__ ell, const int* __restrict__ cnt,
        const float* __restrict__ dinv,
        const ushort_t* __restrict__ Wh, const ushort_t* __restrict__ Wl,
        const float* __restrict__ bias,
        ushort_t* __restrict__ Yh, ushort_t* __restrict__ Yl) {
    __shared__ __align__(16) ushort_t Ah[8 * LDB];
    __shared__ __align__(16) ushort_t Al[8 * LDB];
    int tid = threadIdx.x;
    int lane = tid & 63;
    int w = __builtin_amdgcn_readfirstlane(tid >> 6);
    int row0 = blockIdx.x * 16;
    {
        int r = tid >> 5, cg = tid & 31;
        int row = row0 + r;
        int n = cnt[row];
        int np = (n + 7) & ~7;
        const ushort_t* rell = ell + (size_t)row * ELLW;
        const ushort_t* xb = Xh_ + cg * 8;
        float a[8] = {};
        for (int i = 0; i < np; i += 4) {
            ushort4 ja = *(const ushort4*)&rell[i];
            uint4 u0 = *(const uint4*)&xb[(size_t)ja.x * 256];
            uint4 u1 = *(const uint4*)&xb[(size_t)ja.y * 256];
            uint4 u2 = *(const uint4*)&xb[(size_t)ja.z * 256];
            uint4 u3 = *(const uint4*)&xb[(size_t)ja.w * 256];
            acc_u4(u0, a); acc_u4(u1, a); acc_u4(u2, a); acc_u4(u3, a);
        }
        float dv = dinv[row];
        size_t so = (size_t)row * 256 + cg * 8;
        uint4 h0 = *(const uint4*)&Xh_[so];
        uint4 l0 = *(const uint4*)&Xl_[so];
        short8_t gh, gl;
        pack_pair(h0, l0, a, dv, gh, gl);
        // frag addr: k = cg*8 + j -> c = cg>>2, fq = cg&3, jn = j
        int addr = (cg >> 2) * LDB + ((cg & 3) * 16 + r) * 8;
        *(short8_t*)&Ah[addr] = gh;
        *(short8_t*)&Al[addr] = gl;
    }
    __syncthreads();
    f32x4 acc[2];
    acc_zero16<2>(acc);
    band_step16<2>(Ah, Al, Wh, Wl, w, lane, acc);
    int fr = lane & 15, fq = lane >> 4;
    int col0 = w * 32;
    #pragma unroll
    for (int nt = 0; nt < 2; ++nt) {
        int gc = col0 + 16 * nt + fr;
        float bb = bias[gc];
        #pragma unroll
        for (int e = 0; e < 4; ++e) {
            int gr = row0 + fq * 4 + e;
            float v = fmaxf(acc[nt][e] + bb, 0.0f);   // gl always relu
            size_t off = (size_t)gr * 256 + gc;
            ushort_t h = f2bf(v);
            Yh[off] = h;
            Yl[off] = f2bf(v - bf2f(h));
        }
    }
}

// ---------------- fused output: gout -> proj(relu) -> hc1(relu) -> hc2 + mean ---
__global__ __launch_bounds__(512) void fused_out_kernel(
        const ushort_t* __restrict__ Xh_, const ushort_t* __restrict__ Xl_,
        const ushort_t* __restrict__ Wh, const ushort_t* __restrict__ Wl,
        const float* __restrict__ gout_b, const float* __restrict__ proj_b,
        const float* __restrict__ hc_w1, const float* __restrict__ hc_b1,
        const float* __restrict__ hc_w2, const float* __restrict__ hc_b2,
        float* __restrict__ ne, float* __restrict__ logits, float* __restrict__ gf) {
    __shared__ __align__(16) char arena[33792 + 8448 + 4352];
    ushort_t* Ah = (ushort_t*)arena;                    // 8320 B (MFMA phases)
    ushort_t* Al = (ushort_t*)(arena + 8320);           // 8320 B (MFMA phases)
    float* WL = (float*)arena;                          // 33792 B (hc1 phase), aliases Ah/Al
    float* Pf = (float*)(arena + 33792);                // 16 x 132 f32
    float* T1 = (float*)(arena + 33792 + 8448);         // 16 x 68 f32
    int tid = threadIdx.x;
    int lane = tid & 63;
    int w = __builtin_amdgcn_readfirstlane(tid >> 6);
    int row0 = blockIdx.x * 16;
    int fr = lane & 15, fq = lane >> 4;
    stage_pair16(Xh_, Xl_, row0, tid, Ah, Al);
    __syncthreads();

    // gout (no relu) -> frag LDS pair
    f32x4 acc[2];
    acc_zero16<2>(acc);
    band_step16<2>(Ah, Al, Wh + 393216, Wl + 393216, w, lane, acc);
    __syncthreads();
    acc_to_lds16<2, false>(acc, gout_b, w, lane, Ah, Al);
    __syncthreads();

    // proj (relu), Mcols=128: 8 waves x 16 cols
    f32x4 acc2[1];
    acc_zero16<1>(acc2);
    band_step16<1>(Ah, Al, Wh + 458752, Wl + 458752, w, lane, acc2);
    __syncthreads();   // all Ah/Al reads done -> safe to overwrite with WL

    // write proj -> ne + Pf; concurrently stage hc_w1 -> WL (disjoint regions)
    {
        int gc = w * 16 + fr;
        float bb = proj_b[gc];
        #pragma unroll
        for (int e = 0; e < 4; ++e) {
            int r = fq * 4 + e;
            float v = fmaxf(acc2[0][e] + bb, 0.0f);
            ne[(size_t)(row0 + r) * 128 + gc] = v;
            Pf[r * 132 + gc] = v;
        }
    }
    #pragma unroll
    for (int i = 0; i < 4; ++i) {
        int j4 = i * 512 + tid;            // 2048 float4 slots (64 x 32)
        int m = j4 >> 5, k4 = j4 & 31;
        float4 v = *(const float4*)&hc_w1[(size_t)m * 128 + k4 * 4];
        *(float4*)&WL[m * 132 + k4 * 4] = v;
    }
    __syncthreads();

    // hc1 (relu): 16 rows x 64 cols; thread = (row r, cg of 32); col = jj*32+cg
    {
        int r = tid >> 5, cg = tid & 31;
        float a2[2];
        #pragma unroll
        for (int jj = 0; jj < 2; ++jj) a2[jj] = hc_b1[jj * 32 + cg];
        for (int k4 = 0; k4 < 32; ++k4) {
            float4 x = *(const float4*)&Pf[r * 132 + k4 * 4];
            #pragma unroll
            for (int jj = 0; jj < 2; ++jj) {
                float4 wv = *(const float4*)&WL[(jj * 32 + cg) * 132 + k4 * 4];
                a2[jj] += x.x * wv.x + x.y * wv.y + x.z * wv.z + x.w * wv.w;
            }
        }
        #pragma unroll
        for (int jj = 0; jj < 2; ++jj)
            T1[r * 68 + jj * 32 + cg] = fmaxf(a2[jj], 0.0f);
    }
    __syncthreads();

    // hc2: 16x8 logits
    if (tid < 128) {
        int r = tid >> 3, m = tid & 7;
        float s = hc_b2[m];
        #pragma unroll
        for (int k4 = 0; k4 < 16; ++k4) {
            float4 x = *(const float4*)&T1[r * 68 + k4 * 4];
            float4 wv = *(const float4*)&hc_w2[(size_t)m * 64 + k4 * 4];
            s += x.x * wv.x + x.y * wv.y + x.z * wv.z + x.w * wv.w;
        }
        logits[(size_t)(row0 + r) * 8 + m] = s;
    }

    // column-mean partial of ne band
    if (tid >= 128 && tid < 256) {
        int col = tid - 128;
        float s = 0.0f;
        #pragma unroll 4
        for (int r = 0; r < 16; ++r) s += Pf[r * 132 + col];
        atomicAdd(&gf[col], s * (1.0f / (float)NNODES));
    }
}

extern "C" void kernel_launch(void* const* d_in, const int* in_sizes, int n_in,
                              void* d_out, int out_size, void* d_ws, size_t ws_size,
                              hipStream_t stream) {
    const int N = NNODES;
    const float* nf     = (const float*)d_in[0];
    const int*   ei     = (const int*)d_in[1];
    const float* enc_w1 = (const float*)d_in[2];
    const float* enc_b1 = (const float*)d_in[3];
    const float* enc_w2 = (const float*)d_in[4];
    const float* enc_b2 = (const float*)d_in[5];
    const float* gin_w  = (const float*)d_in[6];
    const float* gin_b  = (const float*)d_in[7];
    const float* gl_w   = (const float*)d_in[8];
    const float* gl_b   = (const float*)d_in[9];
    const float* gout_w = (const float*)d_in[10];
    const float* gout_b = (const float*)d_in[11];
    const float* proj_w = (const float*)d_in[12];
    const float* proj_b = (const float*)d_in[13];
    const float* hc_w1  = (const float*)d_in[14];
    const float* hc_b1  = (const float*)d_in[15];
    const float* hc_w2  = (const float*)d_in[16];
    const float* hc_b2  = (const float*)d_in[17];
    const int E = in_sizes[1] >> 1;

    // workspace carve (bytes) -- NO aliasing now (ws is 256 MiB):
    char* ws = (char*)d_ws;
    u64* M  = (u64*)ws;                                         // 18,874,368
    u64* MT = (u64*)(ws + 18874368);                            // 18,874,368
    ushort_t* XAh = (ushort_t*)(ws + 37748736);                 //  6,295,552
    ushort_t* XAl = (ushort_t*)(ws + 44044288);                 //  6,295,552
    ushort_t* XBh = (ushort_t*)(ws + 50339840);                 //  6,295,552
    ushort_t* XBl = (ushort_t*)(ws + 56635392);                 //  6,295,552
    ushort_t* ell = (ushort_t*)(ws + 62930944);                 //  6,291,456
    int*      cntb = (int*)(ws + 69222400);                     //     49,152
    float*    dinv = (float*)(ws + 69271552);                   //     49,152
    ushort_t* Whi  = (ushort_t*)(ws + 69320704);                //    983,040
    ushort_t* Wlo  = (ushort_t*)(ws + 70303744);                //    983,040

    float* ne     = (float*)d_out;                        // [N,128]
    float* logits = ne + (size_t)N * 128;                 // [N,8]
    float* gf     = logits + (size_t)N * 8;               // [128]

    hipMemsetAsync(M, 0, 2 * (size_t)N * WORDS * sizeof(u64), stream);
    hipMemsetAsync(gf, 0, 128 * sizeof(float), stream);

    // K1: build_mask || wprep || X-pad clear (mutually independent)
    const int nbB = (E + 511) / 512;       // 768 for E=393216
    prep_kernel<<<nbB + 960 + 1, 512, 0, stream>>>(
        ei, E, nbB, M, MT,
        enc_w1, enc_w2, gin_w, gl_w, gout_w, proj_w,
        Whi, Wlo, XAh, XAl, XBh, XBl);

    // K2: fused encoder (768 blocks) || ell_fill (1536 blocks, 8 rows each)
    enc_ell_kernel<<<768 + N / 8, 512, 0, stream>>>(
        nf, Whi, Wlo, enc_b1, enc_b2, gin_b, XAh, XAl,
        M, MT, ell, cntb, dinv);

    const int GB = N / 16;   // 768 band blocks
    // 3 GNN layers, each a single fused gather+GEMM kernel, ping-pong XA<->XB
    fused_layer_kernel<<<GB, 512, 0, stream>>>(XAh, XAl, ell, cntb, dinv,
                                               Whi + 196608, Wlo + 196608,
                                               gl_b, XBh, XBl);
    fused_layer_kernel<<<GB, 512, 0, stream>>>(XBh, XBl, ell, cntb, dinv,
                                               Whi + 262144, Wlo + 262144,
                                               gl_b + 256, XAh, XAl);
    fused_layer_kernel<<<GB, 512, 0, stream>>>(XAh, XAl, ell, cntb, dinv,
                                               Whi + 327680, Wlo + 327680,
                                               gl_b + 512, XBh, XBl);

    // output chain fused: XB -> ne, logits, gf
    fused_out_kernel<<<GB, 512, 0, stream>>>(
        XBh, XBl, Whi, Wlo, gout_b, proj_b, hc_w1, hc_b1, hc_w2, hc_b2,
        ne, logits, gf);
}

// Round 4
// 293.880 us; speedup vs baseline: 1.1541x; 1.0248x over previous
//
#include <hip/hip_runtime.h>

typedef unsigned long long u64;
typedef unsigned short ushort_t;
typedef unsigned int uint32;

#define NNODES 12288
#define WORDS 192    // 12288 / 64 bits per row
#define ELLW 256     // max neighbors per row (avg ~64)
#define ZROW NNODES  // zeroed pad row index
#define LDB 520      // LDS A-frag c-block stride in shorts (bank-rotates 4 words/block)

typedef __attribute__((ext_vector_type(8))) short short8_t;   // 8 bf16 (4 VGPRs)
typedef __attribute__((ext_vector_type(4))) float f32x4;      // MFMA C/D frag
typedef __attribute__((ext_vector_type(2))) float f32x2;      // packed-add pair

// ---- bf16 split helpers (RNE) ----
__device__ __forceinline__ ushort_t f2bf(float f) {
    uint32 u = __float_as_uint(f);
    return (ushort_t)((u + 0x7fffu + ((u >> 16) & 1u)) >> 16);
}
__device__ __forceinline__ float bf2f(ushort_t h) {
    return __uint_as_float(((uint32)h) << 16);
}

// ---------------- K1: build_mask || wprep || X-pad clear ----------------
__global__ __launch_bounds__(512) void prep_kernel(
        const int* __restrict__ ei, int E, int nbB,
        u64* __restrict__ M, u64* __restrict__ MT,
        const float* __restrict__ e1, const float* __restrict__ e2,
        const float* __restrict__ gi, const float* __restrict__ gl,
        const float* __restrict__ go, const float* __restrict__ pj,
        ushort_t* __restrict__ hi, ushort_t* __restrict__ lo,
        ushort_t* __restrict__ xah, ushort_t* __restrict__ xal,
        ushort_t* __restrict__ xbh, ushort_t* __restrict__ xbl) {
    int b = blockIdx.x;
    int t = threadIdx.x;
    if (b < nbB) {
        int e = b * 512 + t;
        if (e >= E) return;
        int s = ei[e];
        int d = ei[E + e];
        atomicOr(&M[(size_t)s * WORDS + (d >> 6)], 1ull << (d & 63));
        atomicOr(&MT[(size_t)d * WORDS + (s >> 6)], 1ull << (s & 63));
        return;
    }
    if (b == nbB + 960) {
        #pragma unroll
        for (int k = 0; k < 4; ++k) {
            size_t off = (size_t)NNODES * 256 + (size_t)k * 512 + t;
            xah[off] = 0; xal[off] = 0; xbh[off] = 0; xbl[off] = 0;
        }
        return;
    }
    int i = (b - nbB) * 512 + t;           // [0, 491520) exactly
    float v;
    if (i < 131072)      v = (i < 65536) ? e1[i] : e2[i - 65536];
    else if (i < 196608) v = gi[i - 131072];
    else if (i < 393216) v = gl[i - 196608];
    else if (i < 458752) v = go[i - 393216];
    else                 v = pj[i - 458752];
    int base = (i < 458752) ? (i & ~65535) : 458752;
    int r = i - base;
    int col = r >> 8, k = r & 255;
    int ct = col >> 4, fr = col & 15;
    int c = k >> 5, fq = (k >> 3) & 3, j = k & 7;
    int o = base + (ct * 8 + c) * 512 + (fq * 16 + fr) * 8 + j;
    ushort_t h = f2bf(v);
    hi[o] = h;
    lo[o] = f2bf(v - bf2f(h));
}

// ---------------- gather accumulate helpers ----------------
__device__ __forceinline__ void acc_u4(uint4 u, f32x2* a2) {
    const uint32 HM = 0xFFFF0000u;
    f32x2 t0 = {__uint_as_float(u.x << 16), __uint_as_float(u.x & HM)};
    f32x2 t1 = {__uint_as_float(u.y << 16), __uint_as_float(u.y & HM)};
    f32x2 t2 = {__uint_as_float(u.z << 16), __uint_as_float(u.z & HM)};
    f32x2 t3 = {__uint_as_float(u.w << 16), __uint_as_float(u.w & HM)};
    a2[0] += t0; a2[1] += t1; a2[2] += t2; a2[3] += t3;
}

// combine self (hi+lo) + dv*acc over 8 cols, split back into bf16 hi/lo octets
__device__ __forceinline__ void pack_pair(uint4 uh, uint4 ul, const float* a, float dv,
                                          short8_t& oh, short8_t& ol) {
    const uint32 HM = 0xFFFF0000u;
    uint32 hu[4] = {uh.x, uh.y, uh.z, uh.w};
    uint32 lu[4] = {ul.x, ul.y, ul.z, ul.w};
    #pragma unroll
    for (int q = 0; q < 4; ++q) {
        float xlo = __uint_as_float(hu[q] << 16) + __uint_as_float(lu[q] << 16);
        float xhi = __uint_as_float(hu[q] & HM) + __uint_as_float(lu[q] & HM);
        float s0 = xlo + dv * a[2 * q];
        float s1 = xhi + dv * a[2 * q + 1];
        ushort_t p0 = f2bf(s0), p1 = f2bf(s1);
        oh[2 * q]     = (short)p0;
        oh[2 * q + 1] = (short)p1;
        ol[2 * q]     = (short)f2bf(s0 - bf2f(p0));
        ol[2 * q + 1] = (short)f2bf(s1 - bf2f(p1));
    }
}

// ---------------- 16-row band-GEMM (frag-swizzled A in LDS, B from L2) -------
// A-frag LDS: 8 c-blocks (k octet-pairs), addr = c*LDB + (fq*16 + r)*8 + j
template<int NTW>
__device__ __forceinline__ void band_step16(
        const ushort_t* Ah, const ushort_t* Al,
        const ushort_t* __restrict__ Wh, const ushort_t* __restrict__ Wl,
        int w, int lane, f32x4 (&acc)[NTW]) {
    int ct0 = w * NTW;
    short8_t bh[NTW], bl[NTW];
    #pragma unroll
    for (int nt = 0; nt < NTW; ++nt) {
        size_t bo = (size_t)((ct0 + nt) * 8) * 512 + lane * 8;
        bh[nt] = *(const short8_t*)&Wh[bo];
        bl[nt] = *(const short8_t*)&Wl[bo];
    }
    #pragma unroll
    for (int c = 0; c < 8; ++c) {
        short8_t bhn[NTW], bln[NTW];
        if (c < 7) {
            #pragma unroll
            for (int nt = 0; nt < NTW; ++nt) {
                size_t bo = (size_t)((ct0 + nt) * 8 + c + 1) * 512 + lane * 8;
                bhn[nt] = *(const short8_t*)&Wh[bo];
                bln[nt] = *(const short8_t*)&Wl[bo];
            }
        }
        short8_t ah = *(const short8_t*)&Ah[c * LDB + lane * 8];
        short8_t al = *(const short8_t*)&Al[c * LDB + lane * 8];
        #pragma unroll
        for (int nt = 0; nt < NTW; ++nt) {
            f32x4 a = acc[nt];
            a = __builtin_amdgcn_mfma_f32_16x16x32_bf16(ah, bh[nt], a, 0, 0, 0);
            a = __builtin_amdgcn_mfma_f32_16x16x32_bf16(ah, bl[nt], a, 0, 0, 0);
            a = __builtin_amdgcn_mfma_f32_16x16x32_bf16(al, bh[nt], a, 0, 0, 0);
            acc[nt] = a;
        }
        if (c < 7) {
            #pragma unroll
            for (int nt = 0; nt < NTW; ++nt) { bh[nt] = bhn[nt]; bl[nt] = bln[nt]; }
        }
    }
}

template<int NTW>
__device__ __forceinline__ void acc_zero16(f32x4 (&acc)[NTW]) {
    #pragma unroll
    for (int b = 0; b < NTW; ++b) {
        f32x4 z = {0.f, 0.f, 0.f, 0.f};
        acc[b] = z;
    }
}

// bias + optional relu, split to hi/lo, store in FRAG layout for next step
template<int NTW, bool RELU>
__device__ __forceinline__ void acc_to_lds16(
        f32x4 (&acc)[NTW], const float* __restrict__ bias,
        int w, int lane, ushort_t* Ah, ushort_t* Al) {
    int fr = lane & 15, fq = lane >> 4;
    int col0 = w * (16 * NTW);
    #pragma unroll
    for (int nt = 0; nt < NTW; ++nt) {
        int col = col0 + 16 * nt + fr;         // next-step k index
        float bb = bias[col];
        int c = col >> 5, fqn = (col >> 3) & 3, jn = col & 7;
        #pragma unroll
        for (int e = 0; e < 4; ++e) {
            int r = fq * 4 + e;                // 0..15
            float v = acc[nt][e] + bb;
            if (RELU) v = fmaxf(v, 0.0f);
            ushort_t h = f2bf(v);
            int addr = c * LDB + (fqn * 16 + r) * 8 + jn;
            Ah[addr] = h;
            Al[addr] = f2bf(v - bf2f(h));
        }
    }
}

// ---------------- gather one 16-row band into FRAG LDS ----------------
// thread = (row r = tid>>5, cg = tid&31): owns cols [cg*8, cg*8+8).
// 8 data loads in flight + next-iteration index prefetch (latency off the
// critical chain). Per-column accumulation order = ELL order -> bitwise
// identical to prior rounds. Worst-case index prefetch reads spill past the
// ELL row into the adjacent (allocated) region; those values are never used.
__device__ __forceinline__ void gather_band(
        const ushort_t* __restrict__ Xh_, const ushort_t* __restrict__ Xl_,
        const ushort_t* __restrict__ ell, const int* __restrict__ cnt,
        const float* __restrict__ dinv, int row0, int tid,
        ushort_t* Ah, ushort_t* Al) {
    int r = tid >> 5, cg = tid & 31;
    int row = row0 + r;
    int n = cnt[row];
    int np8 = (n + 7) & ~7;
    const ushort_t* rell = ell + (size_t)row * ELLW;
    const ushort_t* xb = Xh_ + cg * 8;
    f32x2 a2[4] = {};
    ushort4 ja = *(const ushort4*)&rell[0];
    ushort4 jb = *(const ushort4*)&rell[4];
    for (int i = 0; i < np8; i += 8) {
        ushort4 jan = *(const ushort4*)&rell[i + 8];
        ushort4 jbn = *(const ushort4*)&rell[i + 12];
        uint4 u0 = *(const uint4*)&xb[(size_t)ja.x * 256];
        uint4 u1 = *(const uint4*)&xb[(size_t)ja.y * 256];
        uint4 u2 = *(const uint4*)&xb[(size_t)ja.z * 256];
        uint4 u3 = *(const uint4*)&xb[(size_t)ja.w * 256];
        uint4 u4 = *(const uint4*)&xb[(size_t)jb.x * 256];
        uint4 u5 = *(const uint4*)&xb[(size_t)jb.y * 256];
        uint4 u6 = *(const uint4*)&xb[(size_t)jb.z * 256];
        uint4 u7 = *(const uint4*)&xb[(size_t)jb.w * 256];
        acc_u4(u0, a2); acc_u4(u1, a2); acc_u4(u2, a2); acc_u4(u3, a2);
        acc_u4(u4, a2); acc_u4(u5, a2); acc_u4(u6, a2); acc_u4(u7, a2);
        ja = jan; jb = jbn;
    }
    const float* a = (const float*)a2;
    float dv = dinv[row];
    size_t so = (size_t)row * 256 + cg * 8;
    uint4 h0 = *(const uint4*)&Xh_[so];
    uint4 l0 = *(const uint4*)&Xl_[so];
    short8_t gh, gl;
    pack_pair(h0, l0, a, dv, gh, gl);
    // frag addr: k = cg*8 + j -> c = cg>>2, fq = cg&3, jn = j
    int addr = (cg >> 2) * LDB + ((cg & 3) * 16 + r) * 8;
    *(short8_t*)&Ah[addr] = gh;
    *(short8_t*)&Al[addr] = gl;
}

// ---------------- K2: fused encoder || ell_fill ----------------
__global__ __launch_bounds__(512) void enc_ell_kernel(
        const float* __restrict__ nf,
        const ushort_t* __restrict__ Wh, const ushort_t* __restrict__ Wl,
        const float* __restrict__ b1, const float* __restrict__ b2,
        const float* __restrict__ b3,
        ushort_t* __restrict__ xh, ushort_t* __restrict__ xl,
        const u64* __restrict__ M, const u64* __restrict__ MT,
        ushort_t* __restrict__ ell, int* __restrict__ cnt, float* __restrict__ dinv) {
    __shared__ __align__(16) ushort_t Ah[8 * LDB];
    __shared__ __align__(16) ushort_t Al[8 * LDB];
    int tid = threadIdx.x;
    int lane = tid & 63;
    if (blockIdx.x >= 768) {
        // ---- ell_fill branch: one wave per row ----
        int row = (blockIdx.x - 768) * 8 + (tid >> 6);
        const u64* rM  = M  + (size_t)row * WORDS;
        const u64* rMT = MT + (size_t)row * WORDS;
        u64 wm[3], wt[3];
        int pm = 0, pt = 0;
        #pragma unroll
        for (int k = 0; k < 3; ++k) {
            wm[k] = rM[lane + 64 * k];  pm += __popcll(wm[k]);
            wt[k] = rMT[lane + 64 * k]; pt += __popcll(wt[k]);
        }
        int inclM = pm, inclT = pt;
        #pragma unroll
        for (int off = 1; off < 64; off <<= 1) {
            int ym = __shfl_up(inclM, off, 64);
            int yt = __shfl_up(inclT, off, 64);
            if (lane >= off) { inclM += ym; inclT += yt; }
        }
        int exclM = inclM - pm;
        int exclT = inclT - pt;
        int totM = __shfl(inclM, 63, 64);
        int totT = __shfl(inclT, 63, 64);
        ushort_t* out = ell + (size_t)row * ELLW;
        int pos = exclM;
        #pragma unroll
        for (int k = 0; k < 3; ++k) {
            u64 bits = wm[k];
            int base = (lane + 64 * k) << 6;
            while (bits) { out[pos++] = (ushort_t)(base + __builtin_ctzll(bits)); bits &= bits - 1; }
        }
        pos = totM + exclT;
        #pragma unroll
        for (int k = 0; k < 3; ++k) {
            u64 bits = wt[k];
            int base = (lane + 64 * k) << 6;
            while (bits) { out[pos++] = (ushort_t)(base + __builtin_ctzll(bits)); bits &= bits - 1; }
        }
        if (lane == 0) {
            int n = totM + totT;
            int np = (n + 7) & ~7;
            for (int p = n; p < np; ++p) out[p] = (ushort_t)ZROW;
            cnt[row] = n;
            dinv[row] = 1.0f / ((float)n + 1e-8f);
        }
        return;
    }
    // ---- encoder branch ----
    int w = __builtin_amdgcn_readfirstlane(tid >> 6);   // 0..7
    int row0 = blockIdx.x * 16;
    int fr = lane & 15, fq = lane >> 4;

    // stage nf band (16 rows x 64 float4) with on-the-fly hi/lo split
    #pragma unroll
    for (int i = 0; i < 2; ++i) {
        int s = i * 512 + tid;             // 1024 float4 slots
        int r = s >> 6, k4 = s & 63;
        float4 v = *(const float4*)&nf[(size_t)(row0 + r) * 256 + k4 * 4];
        ushort_t h0 = f2bf(v.x), h1 = f2bf(v.y), h2 = f2bf(v.z), h3 = f2bf(v.w);
        int kq = k4 >> 1, half = (k4 & 1) * 4;
        int c = kq >> 2, fqs = kq & 3;
        int addr = c * LDB + (fqs * 16 + r) * 8 + half;
        *(ushort4*)&Ah[addr] = make_ushort4(h0, h1, h2, h3);
        *(ushort4*)&Al[addr] =
            make_ushort4(f2bf(v.x - bf2f(h0)), f2bf(v.y - bf2f(h1)),
                         f2bf(v.z - bf2f(h2)), f2bf(v.w - bf2f(h3)));
    }
    __syncthreads();

    f32x4 acc[2];
    // enc1 (relu)
    acc_zero16<2>(acc);
    band_step16<2>(Ah, Al, Wh, Wl, w, lane, acc);
    __syncthreads();
    acc_to_lds16<2, true>(acc, b1, w, lane, Ah, Al);
    __syncthreads();
    // enc2 (no relu)
    acc_zero16<2>(acc);
    band_step16<2>(Ah, Al, Wh + 65536, Wl + 65536, w, lane, acc);
    __syncthreads();
    acc_to_lds16<2, false>(acc, b2, w, lane, Ah, Al);
    __syncthreads();
    // gin (relu) -> row-major bf16 pair X0
    acc_zero16<2>(acc);
    band_step16<2>(Ah, Al, Wh + 131072, Wl + 131072, w, lane, acc);
    int col0 = w * 32;
    #pragma unroll
    for (int nt = 0; nt < 2; ++nt) {
        int gc = col0 + 16 * nt + fr;
        float bb = b3[gc];
        #pragma unroll
        for (int e = 0; e < 4; ++e) {
            int gr = row0 + fq * 4 + e;
            float v = fmaxf(acc[nt][e] + bb, 0.0f);
            size_t off = (size_t)gr * 256 + gc;
            ushort_t h = f2bf(v);
            xh[off] = h;
            xl[off] = f2bf(v - bf2f(h));
        }
    }
}

// ---------------- fused GNN layer (layers 1,2): gather -> GEMM -> Y ----------
__global__ __launch_bounds__(512, 4) void fused_layer_kernel(
        const ushort_t* __restrict__ Xh_, const ushort_t* __restrict__ Xl_,
        const ushort_t* __restrict__ ell, const int* __restrict__ cnt,
        const float* __restrict__ dinv,
        const ushort_t* __restrict__ Wh, const ushort_t* __restrict__ Wl,
        const float* __restrict__ bias,
        ushort_t* __restrict__ Yh, ushort_t* __restrict__ Yl) {
    __shared__ __align__(16) ushort_t Ah[8 * LDB];
    __shared__ __align__(16) ushort_t Al[8 * LDB];
    int tid = threadIdx.x;
    int lane = tid & 63;
    int w = __builtin_amdgcn_readfirstlane(tid >> 6);
    int row0 = blockIdx.x * 16;
    gather_band(Xh_, Xl_, ell, cnt, dinv, row0, tid, Ah, Al);
    __syncthreads();
    f32x4 acc[2];
    acc_zero16<2>(acc);
    band_step16<2>(Ah, Al, Wh, Wl, w, lane, acc);
    int fr = lane & 15, fq = lane >> 4;
    int col0 = w * 32;
    #pragma unroll
    for (int nt = 0; nt < 2; ++nt) {
        int gc = col0 + 16 * nt + fr;
        float bb = bias[gc];
        #pragma unroll
        for (int e = 0; e < 4; ++e) {
            int gr = row0 + fq * 4 + e;
            float v = fmaxf(acc[nt][e] + bb, 0.0f);   // gl always relu
            size_t off = (size_t)gr * 256 + gc;
            ushort_t h = f2bf(v);
            Yh[off] = h;
            Yl[off] = f2bf(v - bf2f(h));
        }
    }
}

// ------- fused last layer + output: gather -> gl3 -> gout -> proj -> hc -------
__global__ __launch_bounds__(512, 4) void fused_layer_out_kernel(
        const ushort_t* __restrict__ Xh_, const ushort_t* __restrict__ Xl_,
        const ushort_t* __restrict__ ell, const int* __restrict__ cnt,
        const float* __restrict__ dinv,
        const ushort_t* __restrict__ Wh, const ushort_t* __restrict__ Wl,
        const float* __restrict__ gl_b2,
        const float* __restrict__ gout_b, const float* __restrict__ proj_b,
        const float* __restrict__ hc_w1, const float* __restrict__ hc_b1,
        const float* __restrict__ hc_w2, const float* __restrict__ hc_b2,
        float* __restrict__ ne, float* __restrict__ logits, float* __restrict__ gf) {
    __shared__ __align__(16) char arena[33792 + 8448 + 4352];
    ushort_t* Ah = (ushort_t*)arena;                    // 8320 B (MFMA phases)
    ushort_t* Al = (ushort_t*)(arena + 8320);           // 8320 B (MFMA phases)
    float* WL = (float*)arena;                          // 33792 B (hc1 phase), aliases Ah/Al
    float* Pf = (float*)(arena + 33792);                // 16 x 132 f32
    float* T1 = (float*)(arena + 33792 + 8448);         // 16 x 68 f32
    int tid = threadIdx.x;
    int lane = tid & 63;
    int w = __builtin_amdgcn_readfirstlane(tid >> 6);
    int row0 = blockIdx.x * 16;
    int fr = lane & 15, fq = lane >> 4;

    // layer-3 gather (into frag LDS) + GEMM; result stays on-chip
    gather_band(Xh_, Xl_, ell, cnt, dinv, row0, tid, Ah, Al);
    __syncthreads();
    f32x4 acc[2];
    acc_zero16<2>(acc);
    band_step16<2>(Ah, Al, Wh + 327680, Wl + 327680, w, lane, acc);
    __syncthreads();
    // relu + bf16 hi/lo split into frag LDS -- bit-identical to the old
    // global Y write + stage_pair16 reload (same rounding, same addressing)
    acc_to_lds16<2, true>(acc, gl_b2, w, lane, Ah, Al);
    __syncthreads();

    // gout (no relu) -> frag LDS pair
    acc_zero16<2>(acc);
    band_step16<2>(Ah, Al, Wh + 393216, Wl + 393216, w, lane, acc);
    __syncthreads();
    acc_to_lds16<2, false>(acc, gout_b, w, lane, Ah, Al);
    __syncthreads();

    // proj (relu), Mcols=128: 8 waves x 16 cols
    f32x4 acc2[1];
    acc_zero16<1>(acc2);
    band_step16<1>(Ah, Al, Wh + 458752, Wl + 458752, w, lane, acc2);
    __syncthreads();   // all Ah/Al reads done -> safe to overwrite with WL

    // write proj -> ne + Pf; concurrently stage hc_w1 -> WL (disjoint regions)
    {
        int gc = w * 16 + fr;
        float bb = proj_b[gc];
        #pragma unroll
        for (int e = 0; e < 4; ++e) {
            int r = fq * 4 + e;
            float v = fmaxf(acc2[0][e] + bb, 0.0f);
            ne[(size_t)(row0 + r) * 128 + gc] = v;
            Pf[r * 132 + gc] = v;
        }
    }
    #pragma unroll
    for (int i = 0; i < 4; ++i) {
        int j4 = i * 512 + tid;            // 2048 float4 slots (64 x 32)
        int m = j4 >> 5, k4 = j4 & 31;
        float4 v = *(const float4*)&hc_w1[(size_t)m * 128 + k4 * 4];
        *(float4*)&WL[m * 132 + k4 * 4] = v;
    }
    __syncthreads();

    // hc1 (relu): 16 rows x 64 cols; thread = (row r, cg of 32); col = jj*32+cg
    {
        int r = tid >> 5, cg = tid & 31;
        float a2[2];
        #pragma unroll
        for (int jj = 0; jj < 2; ++jj) a2[jj] = hc_b1[jj * 32 + cg];
        for (int k4 = 0; k4 < 32; ++k4) {
            float4 x = *(const float4*)&Pf[r * 132 + k4 * 4];
            #pragma unroll
            for (int jj = 0; jj < 2; ++jj) {
                float4 wv = *(const float4*)&WL[(jj * 32 + cg) * 132 + k4 * 4];
                a2[jj] += x.x * wv.x + x.y * wv.y + x.z * wv.z + x.w * wv.w;
            }
        }
        #pragma unroll
        for (int jj = 0; jj < 2; ++jj)
            T1[r * 68 + jj * 32 + cg] = fmaxf(a2[jj], 0.0f);
    }
    __syncthreads();

    // hc2: 16x8 logits
    if (tid < 128) {
        int r = tid >> 3, m = tid & 7;
        float s = hc_b2[m];
        #pragma unroll
        for (int k4 = 0; k4 < 16; ++k4) {
            float4 x = *(const float4*)&T1[r * 68 + k4 * 4];
            float4 wv = *(const float4*)&hc_w2[(size_t)m * 64 + k4 * 4];
            s += x.x * wv.x + x.y * wv.y + x.z * wv.z + x.w * wv.w;
        }
        logits[(size_t)(row0 + r) * 8 + m] = s;
    }

    // column-mean partial of ne band
    if (tid >= 128 && tid < 256) {
        int col = tid - 128;
        float s = 0.0f;
        #pragma unroll 4
        for (int r = 0; r < 16; ++r) s += Pf[r * 132 + col];
        atomicAdd(&gf[col], s * (1.0f / (float)NNODES));
    }
}

extern "C" void kernel_launch(void* const* d_in, const int* in_sizes, int n_in,
                              void* d_out, int out_size, void* d_ws, size_t ws_size,
                              hipStream_t stream) {
    const int N = NNODES;
    const float* nf     = (const float*)d_in[0];
    const int*   ei     = (const int*)d_in[1];
    const float* enc_w1 = (const float*)d_in[2];
    const float* enc_b1 = (const float*)d_in[3];
    const float* enc_w2 = (const float*)d_in[4];
    const float* enc_b2 = (const float*)d_in[5];
    const float* gin_w  = (const float*)d_in[6];
    const float* gin_b  = (const float*)d_in[7];
    const float* gl_w   = (const float*)d_in[8];
    const float* gl_b   = (const float*)d_in[9];
    const float* gout_w = (const float*)d_in[10];
    const float* gout_b = (const float*)d_in[11];
    const float* proj_w = (const float*)d_in[12];
    const float* proj_b = (const float*)d_in[13];
    const float* hc_w1  = (const float*)d_in[14];
    const float* hc_b1  = (const float*)d_in[15];
    const float* hc_w2  = (const float*)d_in[16];
    const float* hc_b2  = (const float*)d_in[17];
    const int E = in_sizes[1] >> 1;

    // workspace carve (bytes) -- no aliasing (ws is 256 MiB):
    char* ws = (char*)d_ws;
    u64* M  = (u64*)ws;                                         // 18,874,368
    u64* MT = (u64*)(ws + 18874368);                            // 18,874,368
    ushort_t* XAh = (ushort_t*)(ws + 37748736);                 //  6,295,552
    ushort_t* XAl = (ushort_t*)(ws + 44044288);                 //  6,295,552
    ushort_t* XBh = (ushort_t*)(ws + 50339840);                 //  6,295,552
    ushort_t* XBl = (ushort_t*)(ws + 56635392);                 //  6,295,552
    ushort_t* ell = (ushort_t*)(ws + 62930944);                 //  6,291,456
    int*      cntb = (int*)(ws + 69222400);                     //     49,152
    float*    dinv = (float*)(ws + 69271552);                   //     49,152
    ushort_t* Whi  = (ushort_t*)(ws + 69320704);                //    983,040
    ushort_t* Wlo  = (ushort_t*)(ws + 70303744);                //    983,040

    float* ne     = (float*)d_out;                        // [N,128]
    float* logits = ne + (size_t)N * 128;                 // [N,8]
    float* gf     = logits + (size_t)N * 8;               // [128]

    hipMemsetAsync(M, 0, 2 * (size_t)N * WORDS * sizeof(u64), stream);
    hipMemsetAsync(gf, 0, 128 * sizeof(float), stream);

    // K1: build_mask || wprep || X-pad clear (mutually independent)
    const int nbB = (E + 511) / 512;       // 768 for E=393216
    prep_kernel<<<nbB + 960 + 1, 512, 0, stream>>>(
        ei, E, nbB, M, MT,
        enc_w1, enc_w2, gin_w, gl_w, gout_w, proj_w,
        Whi, Wlo, XAh, XAl, XBh, XBl);

    // K2: fused encoder (768 blocks) || ell_fill (1536 blocks, 8 rows each)
    enc_ell_kernel<<<768 + N / 8, 512, 0, stream>>>(
        nf, Whi, Wlo, enc_b1, enc_b2, gin_b, XAh, XAl,
        M, MT, ell, cntb, dinv);

    const int GB = N / 16;   // 768 band blocks
    // layers 1,2 ping-pong XA<->XB; layer 3 fused with the output chain
    fused_layer_kernel<<<GB, 512, 0, stream>>>(XAh, XAl, ell, cntb, dinv,
                                               Whi + 196608, Wlo + 196608,
                                               gl_b, XBh, XBl);
    fused_layer_kernel<<<GB, 512, 0, stream>>>(XBh, XBl, ell, cntb, dinv,
                                               Whi + 262144, Wlo + 262144,
                                               gl_b + 256, XAh, XAl);
    fused_layer_out_kernel<<<GB, 512, 0, stream>>>(
        XAh, XAl, ell, cntb, dinv, Whi, Wlo, gl_b + 512,
        gout_b, proj_b, hc_w1, hc_b1, hc_w2, hc_b2,
        ne, logits, gf);
}

// Round 5
// 289.142 us; speedup vs baseline: 1.1731x; 1.0164x over previous
//
#include <hip/hip_runtime.h>

typedef unsigned long long u64;
typedef unsigned short ushort_t;
typedef unsigned int uint32;

#define NNODES 12288
#define WORDS 192    // 12288 / 64 bits per row
#define ELLW 256     // max neighbors per row (avg ~64)
#define ZROW NNODES  // zeroed pad row index
#define LDB 520      // LDS A-frag c-block stride in shorts (bank-rotates 4 words/block)
#define RMS 264      // row-major bounce stride in shorts ([16][264], pad kills 4-way wr conflict)
#define HCW1B 491520 // frag base of hc_w1 (64x128) in W buffer
#define HCW2B 507904 // frag base of hc_w2 (8x64, cols 8-15 zeroed)

typedef __attribute__((ext_vector_type(8))) short short8_t;   // 8 bf16 (4 VGPRs)
typedef __attribute__((ext_vector_type(4))) float f32x4;      // MFMA C/D frag
typedef __attribute__((ext_vector_type(2))) float f32x2;      // packed-add pair

// ---- bf16 split helpers (RNE) ----
__device__ __forceinline__ ushort_t f2bf(float f) {
    uint32 u = __float_as_uint(f);
    return (ushort_t)((u + 0x7fffu + ((u >> 16) & 1u)) >> 16);
}
__device__ __forceinline__ float bf2f(ushort_t h) {
    return __uint_as_float(((uint32)h) << 16);
}

// ---------------- K1: build_mask || W swizzle (incl hc) || pad/gf clear ------
__global__ __launch_bounds__(512) void prep_kernel(
        const int* __restrict__ ei, int E, int nbB,
        u64* __restrict__ M, u64* __restrict__ MT,
        const float* __restrict__ e1, const float* __restrict__ e2,
        const float* __restrict__ gi, const float* __restrict__ gl,
        const float* __restrict__ go, const float* __restrict__ pj,
        const float* __restrict__ hw1, const float* __restrict__ hw2,
        ushort_t* __restrict__ hi, ushort_t* __restrict__ lo,
        ushort_t* __restrict__ xah, ushort_t* __restrict__ xal,
        ushort_t* __restrict__ xbh, ushort_t* __restrict__ xbl,
        float* __restrict__ gf) {
    int b = blockIdx.x;
    int t = threadIdx.x;
    if (b < nbB) {
        int e = b * 512 + t;
        if (e >= E) return;
        int s = ei[e];
        int d = ei[E + e];
        atomicOr(&M[(size_t)s * WORDS + (d >> 6)], 1ull << (d & 63));
        atomicOr(&MT[(size_t)d * WORDS + (s >> 6)], 1ull << (s & 63));
        return;
    }
    int wb = b - nbB;
    if (wb < 960) {                       // main W: 491520 elems exactly
        int i = wb * 512 + t;
        float v;
        if (i < 131072)      v = (i < 65536) ? e1[i] : e2[i - 65536];
        else if (i < 196608) v = gi[i - 131072];
        else if (i < 393216) v = gl[i - 196608];
        else if (i < 458752) v = go[i - 393216];
        else                 v = pj[i - 458752];
        int base = (i < 458752) ? (i & ~65535) : 458752;
        int r = i - base;
        int col = r >> 8, k = r & 255;
        int ct = col >> 4, fr = col & 15;
        int c = k >> 5, fq = (k >> 3) & 3, j = k & 7;
        int o = base + (ct * 8 + c) * 512 + (fq * 16 + fr) * 8 + j;
        ushort_t h = f2bf(v);
        hi[o] = h;
        lo[o] = f2bf(v - bf2f(h));
        return;
    }
    if (wb < 976) {                       // hc_w1: 64 cols x 128 k
        int i2 = (wb - 960) * 512 + t;    // [0, 8192)
        int col = i2 >> 7, k = i2 & 127;
        float v = hw1[(size_t)col * 128 + k];
        int o = HCW1B + ((col >> 4) * 8 + (k >> 5)) * 512
              + (((k >> 3) & 3) * 16 + (col & 15)) * 8 + (k & 7);
        ushort_t h = f2bf(v);
        hi[o] = h;
        lo[o] = f2bf(v - bf2f(h));
        return;
    }
    if (wb == 976) {                      // hc_w2: 8 cols x 64 k (+ zero cols 8-15)
        int col = t >> 6, k = t & 63;
        float v = hw2[(size_t)col * 64 + k];
        int o = HCW2B + (k >> 5) * 512 + (((k >> 3) & 3) * 16 + col) * 8 + (k & 7);
        ushort_t h = f2bf(v);
        hi[o] = h;
        lo[o] = f2bf(v - bf2f(h));
        int oz = HCW2B + (k >> 5) * 512 + (((k >> 3) & 3) * 16 + 8 + col) * 8 + (k & 7);
        hi[oz] = 0;
        lo[oz] = 0;
        return;
    }
    // pad rows of X ping-pong pairs + gf zero
    #pragma unroll
    for (int k = 0; k < 4; ++k) {
        size_t off = (size_t)NNODES * 256 + (size_t)k * 512 + t;
        xah[off] = 0; xal[off] = 0; xbh[off] = 0; xbl[off] = 0;
    }
    if (t < 128) gf[t] = 0.0f;
}

// ---------------- gather accumulate helpers ----------------
__device__ __forceinline__ void acc_u4(uint4 u, f32x2* a2) {
    const uint32 HM = 0xFFFF0000u;
    f32x2 t0 = {__uint_as_float(u.x << 16), __uint_as_float(u.x & HM)};
    f32x2 t1 = {__uint_as_float(u.y << 16), __uint_as_float(u.y & HM)};
    f32x2 t2 = {__uint_as_float(u.z << 16), __uint_as_float(u.z & HM)};
    f32x2 t3 = {__uint_as_float(u.w << 16), __uint_as_float(u.w & HM)};
    a2[0] += t0; a2[1] += t1; a2[2] += t2; a2[3] += t3;
}

// combine self (hi+lo) + dv*acc over 8 cols, split back into bf16 hi/lo octets
__device__ __forceinline__ void pack_pair(uint4 uh, uint4 ul, const float* a, float dv,
                                          short8_t& oh, short8_t& ol) {
    const uint32 HM = 0xFFFF0000u;
    uint32 hu[4] = {uh.x, uh.y, uh.z, uh.w};
    uint32 lu[4] = {ul.x, ul.y, ul.z, ul.w};
    #pragma unroll
    for (int q = 0; q < 4; ++q) {
        float xlo = __uint_as_float(hu[q] << 16) + __uint_as_float(lu[q] << 16);
        float xhi = __uint_as_float(hu[q] & HM) + __uint_as_float(lu[q] & HM);
        float s0 = xlo + dv * a[2 * q];
        float s1 = xhi + dv * a[2 * q + 1];
        ushort_t p0 = f2bf(s0), p1 = f2bf(s1);
        oh[2 * q]     = (short)p0;
        oh[2 * q + 1] = (short)p1;
        ol[2 * q]     = (short)f2bf(s0 - bf2f(p0));
        ol[2 * q + 1] = (short)f2bf(s1 - bf2f(p1));
    }
}

// ---------------- 16-row band-GEMM (frag-swizzled A in LDS, B from L2) -------
// A-frag LDS: c-blocks of LDB shorts, addr = c*LDB + (fq*16 + r)*8 + j
// NC = number of K-32 c-blocks (8 for K=256, 4 for K=128, 2 for K=64)
template<int NTW, int NC>
__device__ __forceinline__ void band_step16(
        const ushort_t* Ah, const ushort_t* Al,
        const ushort_t* __restrict__ Wh, const ushort_t* __restrict__ Wl,
        int w, int lane, f32x4 (&acc)[NTW]) {
    int ct0 = w * NTW;
    short8_t bh[NTW], bl[NTW];
    #pragma unroll
    for (int nt = 0; nt < NTW; ++nt) {
        size_t bo = (size_t)((ct0 + nt) * 8) * 512 + lane * 8;
        bh[nt] = *(const short8_t*)&Wh[bo];
        bl[nt] = *(const short8_t*)&Wl[bo];
    }
    #pragma unroll
    for (int c = 0; c < NC; ++c) {
        short8_t bhn[NTW], bln[NTW];
        if (c < NC - 1) {
            #pragma unroll
            for (int nt = 0; nt < NTW; ++nt) {
                size_t bo = (size_t)((ct0 + nt) * 8 + c + 1) * 512 + lane * 8;
                bhn[nt] = *(const short8_t*)&Wh[bo];
                bln[nt] = *(const short8_t*)&Wl[bo];
            }
        }
        short8_t ah = *(const short8_t*)&Ah[c * LDB + lane * 8];
        short8_t al = *(const short8_t*)&Al[c * LDB + lane * 8];
        #pragma unroll
        for (int nt = 0; nt < NTW; ++nt) {
            f32x4 a = acc[nt];
            a = __builtin_amdgcn_mfma_f32_16x16x32_bf16(ah, bh[nt], a, 0, 0, 0);
            a = __builtin_amdgcn_mfma_f32_16x16x32_bf16(ah, bl[nt], a, 0, 0, 0);
            a = __builtin_amdgcn_mfma_f32_16x16x32_bf16(al, bh[nt], a, 0, 0, 0);
            acc[nt] = a;
        }
        if (c < NC - 1) {
            #pragma unroll
            for (int nt = 0; nt < NTW; ++nt) { bh[nt] = bhn[nt]; bl[nt] = bln[nt]; }
        }
    }
}

template<int NTW>
__device__ __forceinline__ void acc_zero16(f32x4 (&acc)[NTW]) {
    #pragma unroll
    for (int b = 0; b < NTW; ++b) {
        f32x4 z = {0.f, 0.f, 0.f, 0.f};
        acc[b] = z;
    }
}

// bias + optional relu, split to hi/lo, store in FRAG layout for next step
template<int NTW, bool RELU>
__device__ __forceinline__ void acc_to_lds16(
        f32x4 (&acc)[NTW], const float* __restrict__ bias,
        int w, int lane, ushort_t* Ah, ushort_t* Al) {
    int fr = lane & 15, fq = lane >> 4;
    int col0 = w * (16 * NTW);
    #pragma unroll
    for (int nt = 0; nt < NTW; ++nt) {
        int col = col0 + 16 * nt + fr;         // next-step k index
        float bb = bias[col];
        int c = col >> 5, fqn = (col >> 3) & 3, jn = col & 7;
        #pragma unroll
        for (int e = 0; e < 4; ++e) {
            int r = fq * 4 + e;                // 0..15
            float v = acc[nt][e] + bb;
            if (RELU) v = fmaxf(v, 0.0f);
            ushort_t h = f2bf(v);
            int addr = c * LDB + (fqn * 16 + r) * 8 + jn;
            Ah[addr] = h;
            Al[addr] = f2bf(v - bf2f(h));
        }
    }
}

// bias + relu, split hi/lo into ROW-MAJOR [16][RMS] bounce buffers
__device__ __forceinline__ void acc_to_rows(
        f32x4 (&acc)[2], const float* __restrict__ bias,
        int w, int lane, ushort_t* Rh, ushort_t* Rl) {
    int fr = lane & 15, fq = lane >> 4;
    int col0 = w * 32;
    #pragma unroll
    for (int nt = 0; nt < 2; ++nt) {
        int gc = col0 + 16 * nt + fr;
        float bb = bias[gc];
        #pragma unroll
        for (int e = 0; e < 4; ++e) {
            int r = fq * 4 + e;
            float v = fmaxf(acc[nt][e] + bb, 0.0f);
            ushort_t h = f2bf(v);
            Rh[r * RMS + gc] = h;
            Rl[r * RMS + gc] = f2bf(v - bf2f(h));
        }
    }
}

// coalesced flush of row-major bounce buffers to global [N][256] pair
__device__ __forceinline__ void rows_to_global(
        const ushort_t* Rh, const ushort_t* Rl, int row0, int tid,
        ushort_t* __restrict__ Yh, ushort_t* __restrict__ Yl) {
    int r = tid >> 5, kq = tid & 31;
    short8_t vh = *(const short8_t*)&Rh[r * RMS + kq * 8];
    short8_t vl = *(const short8_t*)&Rl[r * RMS + kq * 8];
    size_t off = (size_t)(row0 + r) * 256 + kq * 8;
    *(short8_t*)&Yh[off] = vh;
    *(short8_t*)&Yl[off] = vl;
}

// ---------------- gather one 16-row band into FRAG LDS ----------------
__device__ __forceinline__ void gather_band(
        const ushort_t* __restrict__ Xh_, const ushort_t* __restrict__ Xl_,
        const ushort_t* __restrict__ ell, const int* __restrict__ cnt,
        const float* __restrict__ dinv, int row0, int tid,
        ushort_t* Ah, ushort_t* Al) {
    int r = tid >> 5, cg = tid & 31;
    int row = row0 + r;
    int n = cnt[row];
    int np8 = (n + 7) & ~7;
    const ushort_t* rell = ell + (size_t)row * ELLW;
    const ushort_t* xb = Xh_ + cg * 8;
    f32x2 a2[4] = {};
    ushort4 ja = *(const ushort4*)&rell[0];
    ushort4 jb = *(const ushort4*)&rell[4];
    for (int i = 0; i < np8; i += 8) {
        ushort4 jan = *(const ushort4*)&rell[i + 8];
        ushort4 jbn = *(const ushort4*)&rell[i + 12];
        uint4 u0 = *(const uint4*)&xb[(size_t)ja.x * 256];
        uint4 u1 = *(const uint4*)&xb[(size_t)ja.y * 256];
        uint4 u2 = *(const uint4*)&xb[(size_t)ja.z * 256];
        uint4 u3 = *(const uint4*)&xb[(size_t)ja.w * 256];
        uint4 u4 = *(const uint4*)&xb[(size_t)jb.x * 256];
        uint4 u5 = *(const uint4*)&xb[(size_t)jb.y * 256];
        uint4 u6 = *(const uint4*)&xb[(size_t)jb.z * 256];
        uint4 u7 = *(const uint4*)&xb[(size_t)jb.w * 256];
        acc_u4(u0, a2); acc_u4(u1, a2); acc_u4(u2, a2); acc_u4(u3, a2);
        acc_u4(u4, a2); acc_u4(u5, a2); acc_u4(u6, a2); acc_u4(u7, a2);
        ja = jan; jb = jbn;
    }
    const float* a = (const float*)a2;
    float dv = dinv[row];
    size_t so = (size_t)row * 256 + cg * 8;
    uint4 h0 = *(const uint4*)&Xh_[so];
    uint4 l0 = *(const uint4*)&Xl_[so];
    short8_t gh, gl;
    pack_pair(h0, l0, a, dv, gh, gl);
    int addr = (cg >> 2) * LDB + ((cg & 3) * 16 + r) * 8;
    *(short8_t*)&Ah[addr] = gh;
    *(short8_t*)&Al[addr] = gl;
}

// ---------------- K2: fused encoder || ell_fill ----------------
__global__ __launch_bounds__(512) void enc_ell_kernel(
        const float* __restrict__ nf,
        const ushort_t* __restrict__ Wh, const ushort_t* __restrict__ Wl,
        const float* __restrict__ b1, const float* __restrict__ b2,
        const float* __restrict__ b3,
        ushort_t* __restrict__ xh, ushort_t* __restrict__ xl,
        const u64* __restrict__ M, const u64* __restrict__ MT,
        ushort_t* __restrict__ ell, int* __restrict__ cnt, float* __restrict__ dinv) {
    __shared__ __align__(16) ushort_t Ah[16 * RMS];
    __shared__ __align__(16) ushort_t Al[16 * RMS];
    int tid = threadIdx.x;
    int lane = tid & 63;
    if (blockIdx.x >= 768) {
        // ---- ell_fill branch: one wave per row ----
        int row = (blockIdx.x - 768) * 8 + (tid >> 6);
        const u64* rM  = M  + (size_t)row * WORDS;
        const u64* rMT = MT + (size_t)row * WORDS;
        u64 wm[3], wt[3];
        int pm = 0, pt = 0;
        #pragma unroll
        for (int k = 0; k < 3; ++k) {
            wm[k] = rM[lane + 64 * k];  pm += __popcll(wm[k]);
            wt[k] = rMT[lane + 64 * k]; pt += __popcll(wt[k]);
        }
        int inclM = pm, inclT = pt;
        #pragma unroll
        for (int off = 1; off < 64; off <<= 1) {
            int ym = __shfl_up(inclM, off, 64);
            int yt = __shfl_up(inclT, off, 64);
            if (lane >= off) { inclM += ym; inclT += yt; }
        }
        int exclM = inclM - pm;
        int exclT = inclT - pt;
        int totM = __shfl(inclM, 63, 64);
        int totT = __shfl(inclT, 63, 64);
        ushort_t* out = ell + (size_t)row * ELLW;
        int pos = exclM;
        #pragma unroll
        for (int k = 0; k < 3; ++k) {
            u64 bits = wm[k];
            int base = (lane + 64 * k) << 6;
            while (bits) { out[pos++] = (ushort_t)(base + __builtin_ctzll(bits)); bits &= bits - 1; }
        }
        pos = totM + exclT;
        #pragma unroll
        for (int k = 0; k < 3; ++k) {
            u64 bits = wt[k];
            int base = (lane + 64 * k) << 6;
            while (bits) { out[pos++] = (ushort_t)(base + __builtin_ctzll(bits)); bits &= bits - 1; }
        }
        if (lane == 0) {
            int n = totM + totT;
            int np = (n + 7) & ~7;
            for (int p = n; p < np; ++p) out[p] = (ushort_t)ZROW;
            cnt[row] = n;
            dinv[row] = 1.0f / ((float)n + 1e-8f);
        }
        return;
    }
    // ---- encoder branch ----
    int w = __builtin_amdgcn_readfirstlane(tid >> 6);   // 0..7
    int row0 = blockIdx.x * 16;

    // stage nf band (16 rows x 64 float4) with on-the-fly hi/lo split
    #pragma unroll
    for (int i = 0; i < 2; ++i) {
        int s = i * 512 + tid;             // 1024 float4 slots
        int r = s >> 6, k4 = s & 63;
        float4 v = *(const float4*)&nf[(size_t)(row0 + r) * 256 + k4 * 4];
        ushort_t h0 = f2bf(v.x), h1 = f2bf(v.y), h2 = f2bf(v.z), h3 = f2bf(v.w);
        int kq = k4 >> 1, half = (k4 & 1) * 4;
        int c = kq >> 2, fqs = kq & 3;
        int addr = c * LDB + (fqs * 16 + r) * 8 + half;
        *(ushort4*)&Ah[addr] = make_ushort4(h0, h1, h2, h3);
        *(ushort4*)&Al[addr] =
            make_ushort4(f2bf(v.x - bf2f(h0)), f2bf(v.y - bf2f(h1)),
                         f2bf(v.z - bf2f(h2)), f2bf(v.w - bf2f(h3)));
    }
    __syncthreads();

    f32x4 acc[2];
    // enc1 (relu)
    acc_zero16<2>(acc);
    band_step16<2, 8>(Ah, Al, Wh, Wl, w, lane, acc);
    __syncthreads();
    acc_to_lds16<2, true>(acc, b1, w, lane, Ah, Al);
    __syncthreads();
    // enc2 (no relu)
    acc_zero16<2>(acc);
    band_step16<2, 8>(Ah, Al, Wh + 65536, Wl + 65536, w, lane, acc);
    __syncthreads();
    acc_to_lds16<2, false>(acc, b2, w, lane, Ah, Al);
    __syncthreads();
    // gin (relu) -> row-major bounce -> coalesced X0 pair stores
    acc_zero16<2>(acc);
    band_step16<2, 8>(Ah, Al, Wh + 131072, Wl + 131072, w, lane, acc);
    __syncthreads();
    acc_to_rows(acc, b3, w, lane, Ah, Al);
    __syncthreads();
    rows_to_global(Ah, Al, row0, tid, xh, xl);
}

// ---------------- fused GNN layer (layers 1,2): gather -> GEMM -> Y ----------
__global__ __launch_bounds__(512, 4) void fused_layer_kernel(
        const ushort_t* __restrict__ Xh_, const ushort_t* __restrict__ Xl_,
        const ushort_t* __restrict__ ell, const int* __restrict__ cnt,
        const float* __restrict__ dinv,
        const ushort_t* __restrict__ Wh, const ushort_t* __restrict__ Wl,
        const float* __restrict__ bias,
        ushort_t* __restrict__ Yh, ushort_t* __restrict__ Yl) {
    __shared__ __align__(16) ushort_t Ah[16 * RMS];
    __shared__ __align__(16) ushort_t Al[16 * RMS];
    int tid = threadIdx.x;
    int lane = tid & 63;
    int w = __builtin_amdgcn_readfirstlane(tid >> 6);
    int row0 = blockIdx.x * 16;
    gather_band(Xh_, Xl_, ell, cnt, dinv, row0, tid, Ah, Al);
    __syncthreads();
    f32x4 acc[2];
    acc_zero16<2>(acc);
    band_step16<2, 8>(Ah, Al, Wh, Wl, w, lane, acc);
    __syncthreads();                       // frag reads done -> reuse as bounce
    acc_to_rows(acc, bias, w, lane, Ah, Al);
    __syncthreads();
    rows_to_global(Ah, Al, row0, tid, Yh, Yl);
}

// ------- fused last layer + output: gather -> gl3 -> gout -> proj -> hc -------
__global__ __launch_bounds__(512, 4) void fused_layer_out_kernel(
        const ushort_t* __restrict__ Xh_, const ushort_t* __restrict__ Xl_,
        const ushort_t* __restrict__ ell, const int* __restrict__ cnt,
        const float* __restrict__ dinv,
        const ushort_t* __restrict__ Wh, const ushort_t* __restrict__ Wl,
        const float* __restrict__ gl_b2,
        const float* __restrict__ gout_b, const float* __restrict__ proj_b,
        const float* __restrict__ hc_b1, const float* __restrict__ hc_b2,
        float* __restrict__ ne, float* __restrict__ logits, float* __restrict__ gf) {
    __shared__ __align__(16) ushort_t Ah[16 * RMS];   // frag uses first 8*LDB
    __shared__ __align__(16) ushort_t Al[16 * RMS];
    __shared__ __align__(16) float Pf[16 * 132];      // exact f32 proj (ne + mean)
    int tid = threadIdx.x;
    int lane = tid & 63;
    int w = __builtin_amdgcn_readfirstlane(tid >> 6);
    int row0 = blockIdx.x * 16;
    int fr = lane & 15, fq = lane >> 4;

    // layer-3 gather (into frag LDS) + GEMM; result stays on-chip
    gather_band(Xh_, Xl_, ell, cnt, dinv, row0, tid, Ah, Al);
    __syncthreads();
    f32x4 acc[2];
    acc_zero16<2>(acc);
    band_step16<2, 8>(Ah, Al, Wh + 327680, Wl + 327680, w, lane, acc);
    __syncthreads();
    acc_to_lds16<2, true>(acc, gl_b2, w, lane, Ah, Al);
    __syncthreads();

    // gout (no relu) -> frag LDS pair
    acc_zero16<2>(acc);
    band_step16<2, 8>(Ah, Al, Wh + 393216, Wl + 393216, w, lane, acc);
    __syncthreads();
    acc_to_lds16<2, false>(acc, gout_b, w, lane, Ah, Al);
    __syncthreads();

    // proj (relu), 128 cols: 8 waves x 16 cols
    f32x4 acc2[1];
    acc_zero16<1>(acc2);
    band_step16<1, 8>(Ah, Al, Wh + 458752, Wl + 458752, w, lane, acc2);
    __syncthreads();   // all frag reads done

    // proj out -> Pf (exact f32) + frag c0-3 (bf16 pair, hc1 A-operand)
    {
        int gc = w * 16 + fr;
        float bb = proj_b[gc];
        int c = gc >> 5, fqn = (gc >> 3) & 3, jn = gc & 7;
        #pragma unroll
        for (int e = 0; e < 4; ++e) {
            int r = fq * 4 + e;
            float v = fmaxf(acc2[0][e] + bb, 0.0f);
            Pf[r * 132 + gc] = v;
            ushort_t h = f2bf(v);
            int addr = c * LDB + (fqn * 16 + r) * 8 + jn;
            Ah[addr] = h;
            Al[addr] = f2bf(v - bf2f(h));
        }
    }
    __syncthreads();

    // phase: ne bounce (all) || gf mean (tids 128-255) || hc1 MFMA (waves 0-3)
    {
        int r = tid >> 5, k4 = tid & 31;
        float4 x = *(const float4*)&Pf[r * 132 + k4 * 4];
        *(float4*)&ne[(size_t)(row0 + r) * 128 + k4 * 4] = x;
    }
    if (tid >= 128 && tid < 256) {
        int col = tid - 128;
        float s = 0.0f;
        #pragma unroll 4
        for (int r = 0; r < 16; ++r) s += Pf[r * 132 + col];
        atomicAdd(&gf[col], s * (1.0f / (float)NNODES));
    }
    if (w < 4) {
        // hc1 (relu): K=128 (c0-3), 64 cols = 4 waves x 16; out -> frag c4,5
        f32x4 acc3[1];
        acc_zero16<1>(acc3);
        band_step16<1, 4>(Ah, Al, Wh + HCW1B, Wl + HCW1B, w, lane, acc3);
        int col64 = w * 16 + fr;
        float bb = hc_b1[col64];
        int c = 4 + (col64 >> 5), fqn = (col64 >> 3) & 3, jn = col64 & 7;
        #pragma unroll
        for (int e = 0; e < 4; ++e) {
            int r = fq * 4 + e;
            float v = fmaxf(acc3[0][e] + bb, 0.0f);
            ushort_t h = f2bf(v);
            int addr = c * LDB + (fqn * 16 + r) * 8 + jn;
            Ah[addr] = h;
            Al[addr] = f2bf(v - bf2f(h));
        }
    }
    __syncthreads();

    // hc2: K=64 from frag c4,5; one wave; cols 0-7 valid (8-15 zero-padded W)
    if (w == 0) {
        f32x4 acc4[1];
        acc_zero16<1>(acc4);
        band_step16<1, 2>(Ah + 4 * LDB, Al + 4 * LDB,
                          Wh + HCW2B, Wl + HCW2B, 0, lane, acc4);
        if (fr < 8) {
            float bb = hc_b2[fr];
            #pragma unroll
            for (int e = 0; e < 4; ++e) {
                int r = fq * 4 + e;
                logits[(size_t)(row0 + r) * 8 + fr] = acc4[0][e] + bb;
            }
        }
    }
}

extern "C" void kernel_launch(void* const* d_in, const int* in_sizes, int n_in,
                              void* d_out, int out_size, void* d_ws, size_t ws_size,
                              hipStream_t stream) {
    const int N = NNODES;
    const float* nf     = (const float*)d_in[0];
    const int*   ei     = (const int*)d_in[1];
    const float* enc_w1 = (const float*)d_in[2];
    const float* enc_b1 = (const float*)d_in[3];
    const float* enc_w2 = (const float*)d_in[4];
    const float* enc_b2 = (const float*)d_in[5];
    const float* gin_w  = (const float*)d_in[6];
    const float* gin_b  = (const float*)d_in[7];
    const float* gl_w   = (const float*)d_in[8];
    const float* gl_b   = (const float*)d_in[9];
    const float* gout_w = (const float*)d_in[10];
    const float* gout_b = (const float*)d_in[11];
    const float* proj_w = (const float*)d_in[12];
    const float* proj_b = (const float*)d_in[13];
    const float* hc_w1  = (const float*)d_in[14];
    const float* hc_b1  = (const float*)d_in[15];
    const float* hc_w2  = (const float*)d_in[16];
    const float* hc_b2  = (const float*)d_in[17];
    const int E = in_sizes[1] >> 1;

    // workspace carve (bytes) -- no aliasing (ws is 256 MiB):
    char* ws = (char*)d_ws;
    u64* M  = (u64*)ws;                                         // 18,874,368
    u64* MT = (u64*)(ws + 18874368);                            // 18,874,368
    ushort_t* XAh = (ushort_t*)(ws + 37748736);                 //  6,295,552
    ushort_t* XAl = (ushort_t*)(ws + 44044288);                 //  6,295,552
    ushort_t* XBh = (ushort_t*)(ws + 50339840);                 //  6,295,552
    ushort_t* XBl = (ushort_t*)(ws + 56635392);                 //  6,295,552
    ushort_t* ell = (ushort_t*)(ws + 62930944);                 //  6,291,456
    int*      cntb = (int*)(ws + 69222400);                     //     49,152
    float*    dinv = (float*)(ws + 69271552);                   //     49,152
    ushort_t* Whi  = (ushort_t*)(ws + 69320704);                //  1,024,000
    ushort_t* Wlo  = (ushort_t*)(ws + 70344704);                //  1,024,000

    float* ne     = (float*)d_out;                        // [N,128]
    float* logits = ne + (size_t)N * 128;                 // [N,8]
    float* gf     = logits + (size_t)N * 8;               // [128]

    hipMemsetAsync(M, 0, 2 * (size_t)N * WORDS * sizeof(u64), stream);

    // K1: build_mask || W swizzle (incl hc_w1/hc_w2) || pad+gf clear
    const int nbB = (E + 511) / 512;       // 768 for E=393216
    prep_kernel<<<nbB + 978, 512, 0, stream>>>(
        ei, E, nbB, M, MT,
        enc_w1, enc_w2, gin_w, gl_w, gout_w, proj_w, hc_w1, hc_w2,
        Whi, Wlo, XAh, XAl, XBh, XBl, gf);

    // K2: fused encoder (768 blocks) || ell_fill (1536 blocks, 8 rows each)
    enc_ell_kernel<<<768 + N / 8, 512, 0, stream>>>(
        nf, Whi, Wlo, enc_b1, enc_b2, gin_b, XAh, XAl,
        M, MT, ell, cntb, dinv);

    const int GB = N / 16;   // 768 band blocks
    // layers 1,2 ping-pong XA<->XB; layer 3 fused with the output chain
    fused_layer_kernel<<<GB, 512, 0, stream>>>(XAh, XAl, ell, cntb, dinv,
                                               Whi + 196608, Wlo + 196608,
                                               gl_b, XBh, XBl);
    fused_layer_kernel<<<GB, 512, 0, stream>>>(XBh, XBl, ell, cntb, dinv,
                                               Whi + 262144, Wlo + 262144,
                                               gl_b + 256, XAh, XAl);
    fused_layer_out_kernel<<<GB, 512, 0, stream>>>(
        XAh, XAl, ell, cntb, dinv, Whi, Wlo, gl_b + 512,
        gout_b, proj_b, hc_b1, hc_b2,
        ne, logits, gf);
}